// Round 1
// baseline (1130.270 us; speedup 1.0000x reference)
//
#include <hip/hip_runtime.h>

typedef _Float16 f16;
typedef _Float16 f16x8 __attribute__((ext_vector_type(8)));
typedef f16x8 f16x8a __attribute__((may_alias));
typedef float f32x4 __attribute__((ext_vector_type(4)));

#define NTOK 21120          // 4 * 5280 tokens
#define SCALE_Q 0.18033688f // (1/8) * log2(e)

__device__ __forceinline__ void gll16(const void* g, void* l) {
  __builtin_amdgcn_global_load_lds(
      (const __attribute__((address_space(1))) unsigned int*)g,
      (__attribute__((address_space(3))) unsigned int*)l, 16, 0, 0);
}

__device__ __forceinline__ unsigned int pack2(float a, float b) {
  union { f16 h[2]; unsigned int u; } c;
  c.h[0] = (f16)a; c.h[1] = (f16)b;
  return c.u;
}
__device__ __forceinline__ unsigned short f2h(float a) {
  union { f16 h; unsigned short u; } c; c.h = (f16)a; return c.u;
}

// ---------------------------------------------------------------- casts
__global__ __launch_bounds__(256) void cast_kernel(
    const float* __restrict__ in, unsigned short* __restrict__ out, int n4) {
  int i = blockIdx.x * 256 + threadIdx.x;
  if (i >= n4) return;
  float4 v = ((const float4*)in)[i];
  uint2 o;
  o.x = pack2(v.x, v.y);
  o.y = pack2(v.z, v.w);
  ((uint2*)out)[i] = o;
}

// ---------------------------------------------------------------- rope tables
__global__ __launch_bounds__(256) void rope_table_kernel(float2* tabS, float2* tabT) {
  int t = blockIdx.x * 256 + threadIdx.x;
  const float lb = logf(10000.0f) * (1.0f / 32.0f);
  if (t < 220 * 32) {
    int s = t >> 5, i = t & 31;
    float theta = expf(-(float)i * lb);
    float ang = (float)s * theta;
    tabS[t] = make_float2(cosf(ang), sinf(ang));
  } else if (t < 220 * 32 + 24 * 32) {
    int u = t - 220 * 32;
    int s = u >> 5, i = u & 31;
    float theta = expf(-(float)i * lb);
    float ang = (float)s * theta;
    tabT[u] = make_float2(cosf(ang), sinf(ang));
  }
}

// ---------------------------------------------------------------- GEMM  C = A * B^T
// A[M,K], B[N,K] both f16 K-contiguous. outmode: 0 = f16 out, 1 = f16 out + bias,
// 2 = f32 out + bias. M,N multiples of 128; K multiple of 32.
__global__ __launch_bounds__(256) void gemm_bt(
    const unsigned short* __restrict__ A, const unsigned short* __restrict__ B,
    const float* __restrict__ bias, void* __restrict__ C,
    int M, int N, int K, int outmode) {
  __shared__ __align__(16) unsigned short As[4096]; // 128 rows x 32 (64B/row), chunk-swizzled
  __shared__ __align__(16) unsigned short Bs[4096];
  const int tid = threadIdx.x;
  const int w = tid >> 6, lane = tid & 63;
  const int l15 = lane & 15, quad = lane >> 4;
  const int wr = w >> 1, wc = w & 1;
  const int tm = blockIdx.x, tn = blockIdx.y;
  const int i4 = lane >> 2, pp = lane & 3;

  f32x4 acc[4][4];
#pragma unroll
  for (int a = 0; a < 4; ++a)
#pragma unroll
    for (int b = 0; b < 4; ++b) acc[a][b] = (f32x4){0.f, 0.f, 0.f, 0.f};

  int srow[2], scx[2];
#pragma unroll
  for (int c = 0; c < 2; ++c) {
    int r = (c * 4 + w) * 16 + i4;
    srow[c] = r;
    scx[c] = pp ^ ((r & 3) ^ ((r >> 2) & 3));
  }
  const int xr = (l15 & 3) ^ ((l15 >> 2) & 3);
  const size_t arow0 = (size_t)tm * 128;
  const size_t brow0 = (size_t)tn * 128;
  const int nk = K >> 5;

  for (int kt = 0; kt < nk; ++kt) {
    __syncthreads();
    const int kb = kt << 5;
#pragma unroll
    for (int c = 0; c < 2; ++c) {
      gll16(A + (arow0 + srow[c]) * K + kb + scx[c] * 8, (char*)As + (c * 4 + w) * 1024);
      gll16(B + (brow0 + srow[c]) * K + kb + scx[c] * 8, (char*)Bs + (c * 4 + w) * 1024);
    }
    __syncthreads();
    f16x8 af[4], bf[4];
#pragma unroll
    for (int mt = 0; mt < 4; ++mt) {
      int ra = wr * 64 + mt * 16 + l15;
      af[mt] = *(const f16x8a*)((const char*)As + ra * 64 + (quad ^ xr) * 16);
      int rb = wc * 64 + mt * 16 + l15;
      bf[mt] = *(const f16x8a*)((const char*)Bs + rb * 64 + (quad ^ xr) * 16);
    }
#pragma unroll
    for (int mt = 0; mt < 4; ++mt)
#pragma unroll
      for (int nt = 0; nt < 4; ++nt)
        acc[mt][nt] = __builtin_amdgcn_mfma_f32_16x16x32_f16(af[mt], bf[nt], acc[mt][nt], 0, 0, 0);
  }

  const int row0 = tm * 128 + wr * 64 + quad * 4;
  const int col0 = tn * 128 + wc * 64 + l15;
#pragma unroll
  for (int nt = 0; nt < 4; ++nt) {
    int cc = col0 + nt * 16;
    float bvv = 0.0f;
    if (outmode > 0) bvv = bias[cc];
#pragma unroll
    for (int mt = 0; mt < 4; ++mt) {
      int rr = row0 + mt * 16;
#pragma unroll
      for (int rg = 0; rg < 4; ++rg) {
        float v = acc[mt][nt][rg] + bvv;
        if (outmode == 2)
          ((float*)C)[(size_t)(rr + rg) * N + cc] = v;
        else
          ((unsigned short*)C)[(size_t)(rr + rg) * N + cc] = f2h(v);
      }
    }
  }
}

// ---------------------------------------------------------------- spatial attention
// One block per (n, h); n in [0,96), sequences are 220 consecutive tokens.
// qkv layout: [token][3*1024] with e = which*1024 + h*64 + d.
__global__ __launch_bounds__(256) void attn_spatial(
    const unsigned short* __restrict__ qkv, unsigned short* __restrict__ aout,
    const float2* __restrict__ tab, const float* __restrict__ gq,
    const float* __restrict__ gk) {
  __shared__ __align__(16) unsigned short sh[23296];
  unsigned short* Qs = sh;                 // 256 rows x 72 (later aliased by P bufs)
  unsigned short* Ks = sh + 18432;         // 32 x 72
  unsigned short* Vts = sh + 18432 + 2304; // 64 x 40 (V transposed)
  const int tid = threadIdx.x;
  const int w = tid >> 6, lane = tid & 63;
  const int l15 = lane & 15, quad = lane >> 4;
  const int n = blockIdx.x >> 4, h = blockIdx.x & 15;
  const size_t tb = (size_t)n * 220;

  // ---- stage Q: one row per thread, rmsnorm + gain + rope + SCALE_Q ----
  {
    int s = tid;
    unsigned int* Qu = (unsigned int*)Qs + s * 36;
    if (s < 220) {
      const f16x8* src = (const f16x8*)(qkv + (tb + s) * 3072 + h * 64);
      float f[64];
#pragma unroll
      for (int c = 0; c < 8; ++c) {
        f16x8 v = src[c];
#pragma unroll
        for (int j = 0; j < 8; ++j) f[c * 8 + j] = (float)v[j];
      }
      float ssq = 0.f;
#pragma unroll
      for (int j = 0; j < 64; ++j) ssq += f[j] * f[j];
      float rr = rsqrtf(ssq * (1.0f / 64.0f) + 1e-6f);
#pragma unroll
      for (int i = 0; i < 32; ++i) {
        float a = f[2 * i] * rr * gq[2 * i];
        float b = f[2 * i + 1] * rr * gq[2 * i + 1];
        float2 cs = tab[s * 32 + i];
        Qu[i] = pack2((a * cs.x - b * cs.y) * SCALE_Q, (b * cs.x + a * cs.y) * SCALE_Q);
      }
    } else {
#pragma unroll
      for (int i = 0; i < 32; ++i) Qu[i] = 0;
    }
  }
  __syncthreads();

  // ---- load Q fragments (A-operand: m = l15, k = quad*8+j, two 32-k chunks) ----
  f16x8 aq[4][2];
#pragma unroll
  for (int mt = 0; mt < 4; ++mt) {
    const char* base = (const char*)Qs + (w * 64 + mt * 16 + l15) * 144;
    aq[mt][0] = *(const f16x8a*)(base + quad * 16);
    aq[mt][1] = *(const f16x8a*)(base + 64 + quad * 16);
  }
  __syncthreads(); // Qs now free -> P buffers alias it

  float mrow[4][4], lrow[4][4];
  f32x4 o[4][4];
#pragma unroll
  for (int mt = 0; mt < 4; ++mt)
#pragma unroll
    for (int rg = 0; rg < 4; ++rg) { mrow[mt][rg] = -1e30f; lrow[mt][rg] = 0.f; }
#pragma unroll
  for (int mt = 0; mt < 4; ++mt)
#pragma unroll
    for (int nt = 0; nt < 4; ++nt) o[mt][nt] = (f32x4){0.f, 0.f, 0.f, 0.f};

  const int xr = (l15 & 3) ^ ((l15 >> 2) & 3);
  unsigned short* Pw = Qs + w * 2048; // per-wave 64 rows x 32 f16, chunk-swizzled

  for (int ci = 0; ci < 7; ++ci) {
    __syncthreads();
    // ---- stage K chunk (rows 0..31 <-> keys ci*32+r), rmsnorm+gain+rope ----
    if (tid < 64) {
      int r = tid >> 1, hf = tid & 1;
      int key = ci * 32 + r;
      unsigned int* Ku = (unsigned int*)Ks + r * 36 + hf * 16;
      if (key < 220) {
        const f16x8* src = (const f16x8*)(qkv + (tb + key) * 3072 + 1024 + h * 64 + hf * 32);
        float f[32];
#pragma unroll
        for (int c = 0; c < 4; ++c) {
          f16x8 v = src[c];
#pragma unroll
          for (int j = 0; j < 8; ++j) f[c * 8 + j] = (float)v[j];
        }
        float ssq = 0.f;
#pragma unroll
        for (int j = 0; j < 32; ++j) ssq += f[j] * f[j];
        ssq += __shfl_xor(ssq, 1);
        float rr = rsqrtf(ssq * (1.0f / 64.0f) + 1e-6f);
#pragma unroll
        for (int i = 0; i < 16; ++i) {
          int gi = hf * 16 + i;
          float a = f[2 * i] * rr * gk[2 * gi];
          float b = f[2 * i + 1] * rr * gk[2 * gi + 1];
          float2 cs = tab[key * 32 + gi];
          Ku[i] = pack2(a * cs.x - b * cs.y, b * cs.x + a * cs.y);
        }
      } else {
#pragma unroll
        for (int i = 0; i < 16; ++i) Ku[i] = 0;
      }
    } else if (tid < 192) {
      // ---- stage V chunk transposed: Vts[d][r], r = key-in-chunk ----
      int u = tid - 64;
      int r = u >> 2, qt = u & 3;
      int key = ci * 32 + r;
      if (key < 220) {
        const unsigned short* src = qkv + (tb + key) * 3072 + 2048 + h * 64 + qt * 16;
        union { uint4 q[2]; unsigned short us[16]; } tv;
        tv.q[0] = *(const uint4*)src;
        tv.q[1] = *(const uint4*)(src + 8);
#pragma unroll
        for (int j = 0; j < 16; ++j) Vts[(qt * 16 + j) * 40 + r] = tv.us[j];
      } else {
#pragma unroll
        for (int j = 0; j < 16; ++j) Vts[(qt * 16 + j) * 40 + r] = 0;
      }
    }
    __syncthreads();

    // ---- scores for this 32-key chunk ----
    f16x8 bk[2][2];
#pragma unroll
    for (int ct = 0; ct < 2; ++ct) {
      const char* base = (const char*)Ks + (ct * 16 + l15) * 144;
      bk[ct][0] = *(const f16x8a*)(base + quad * 16);
      bk[ct][1] = *(const f16x8a*)(base + 64 + quad * 16);
    }
    f32x4 sc[4][2];
#pragma unroll
    for (int mt = 0; mt < 4; ++mt)
#pragma unroll
      for (int ct = 0; ct < 2; ++ct) {
        f32x4 z = (f32x4){0.f, 0.f, 0.f, 0.f};
        z = __builtin_amdgcn_mfma_f32_16x16x32_f16(aq[mt][0], bk[ct][0], z, 0, 0, 0);
        sc[mt][ct] = __builtin_amdgcn_mfma_f32_16x16x32_f16(aq[mt][1], bk[ct][1], z, 0, 0, 0);
      }
#pragma unroll
    for (int ct = 0; ct < 2; ++ct) {
      int col = ci * 32 + ct * 16 + l15;
      if (col >= 220) {
#pragma unroll
        for (int mt = 0; mt < 4; ++mt)
#pragma unroll
          for (int rg = 0; rg < 4; ++rg) sc[mt][ct][rg] = -1e30f;
      }
    }
    // ---- online softmax + P store (row = quad*4+rg per C-layout) ----
#pragma unroll
    for (int mt = 0; mt < 4; ++mt)
#pragma unroll
      for (int rg = 0; rg < 4; ++rg) {
        float v0 = sc[mt][0][rg], v1 = sc[mt][1][rg];
        float cm = fmaxf(v0, v1);
        cm = fmaxf(cm, __shfl_xor(cm, 1));
        cm = fmaxf(cm, __shfl_xor(cm, 2));
        cm = fmaxf(cm, __shfl_xor(cm, 4));
        cm = fmaxf(cm, __shfl_xor(cm, 8));
        float mo = mrow[mt][rg];
        float mn = fmaxf(mo, cm);
        float al = exp2f(mo - mn);
        float p0 = exp2f(v0 - mn), p1 = exp2f(v1 - mn);
        float rs = p0 + p1;
        rs += __shfl_xor(rs, 1);
        rs += __shfl_xor(rs, 2);
        rs += __shfl_xor(rs, 4);
        rs += __shfl_xor(rs, 8);
        lrow[mt][rg] = lrow[mt][rg] * al + rs;
        mrow[mt][rg] = mn;
#pragma unroll
        for (int nt = 0; nt < 4; ++nt) o[mt][nt][rg] *= al;
        int prow = mt * 16 + quad * 4 + rg;
        int xw = quad ^ rg; // swizzle key for prow & 15
        unsigned short* pb = Pw + prow * 32;
        pb[(((l15 >> 3) ^ xw) * 8) + (l15 & 7)] = f2h(p0);
        pb[(((2 + (l15 >> 3)) ^ xw) * 8) + (l15 & 7)] = f2h(p1);
      }
    __asm__ volatile("s_waitcnt lgkmcnt(0)" ::: "memory");
    // ---- PV ----
    f16x8 ap[4], bv[4];
#pragma unroll
    for (int mt = 0; mt < 4; ++mt)
      ap[mt] = *(const f16x8a*)((const char*)Pw + (mt * 16 + l15) * 64 + (quad ^ xr) * 16);
#pragma unroll
    for (int nt = 0; nt < 4; ++nt)
      bv[nt] = *(const f16x8a*)((const char*)Vts + (nt * 16 + l15) * 80 + quad * 16);
#pragma unroll
    for (int mt = 0; mt < 4; ++mt)
#pragma unroll
      for (int nt = 0; nt < 4; ++nt)
        o[mt][nt] = __builtin_amdgcn_mfma_f32_16x16x32_f16(ap[mt], bv[nt], o[mt][nt], 0, 0, 0);
  }

  // ---- epilogue ----
#pragma unroll
  for (int mt = 0; mt < 4; ++mt)
#pragma unroll
    for (int rg = 0; rg < 4; ++rg) {
      int s = w * 64 + mt * 16 + quad * 4 + rg;
      if (s < 220) {
        float inv = 1.0f / lrow[mt][rg];
        unsigned short* dst = aout + (tb + s) * 1024 + h * 64;
#pragma unroll
        for (int nt = 0; nt < 4; ++nt) dst[nt * 16 + l15] = f2h(o[mt][nt][rg] * inv);
      }
    }
}

// ---------------------------------------------------------------- temporal attention
// One block per (b, p, hquad); wave w handles head h = hq*4 + w over S=24 frames.
__global__ __launch_bounds__(256) void attn_temporal(
    const unsigned short* __restrict__ qkv, unsigned short* __restrict__ aout,
    const float2* __restrict__ tab, const float* __restrict__ gq,
    const float* __restrict__ gk) {
  __shared__ __align__(16) unsigned short sh[28672]; // 4 waves x 7168
  const int tid = threadIdx.x;
  const int w = tid >> 6, lane = tid & 63;
  const int l15 = lane & 15, quad = lane >> 4;
  const int bi = blockIdx.x;
  const int b = bi / 880;
  const int rem = bi % 880;
  const int p = rem >> 2, hq = rem & 3;
  const int h = hq * 4 + w;
  unsigned short* Qw = sh + w * 7168; // 32 x 72 (aliased by P later)
  unsigned short* Kw = Qw + 2304;     // 32 x 72
  unsigned short* Vw = Qw + 4608;     // 64 x 40 transposed

  // ---- staging: lane covers (frame r = lane>>1, half hf = lane&1) ----
  {
    int r = lane >> 1, hf = lane & 1;
    unsigned int* Qu = (unsigned int*)Qw + r * 36 + hf * 16;
    unsigned int* Ku = (unsigned int*)Kw + r * 36 + hf * 16;
    if (r < 24) {
      size_t trow = ((size_t)(b * 24 + r) * 220 + p) * 3072 + h * 64 + hf * 32;
      {
        const f16x8* src = (const f16x8*)(qkv + trow);
        float f[32];
#pragma unroll
        for (int c = 0; c < 4; ++c) {
          f16x8 v = src[c];
#pragma unroll
          for (int j = 0; j < 8; ++j) f[c * 8 + j] = (float)v[j];
        }
        float ssq = 0.f;
#pragma unroll
        for (int j = 0; j < 32; ++j) ssq += f[j] * f[j];
        ssq += __shfl_xor(ssq, 1);
        float rr = rsqrtf(ssq * (1.0f / 64.0f) + 1e-6f);
#pragma unroll
        for (int i = 0; i < 16; ++i) {
          int gi = hf * 16 + i;
          float a = f[2 * i] * rr * gq[2 * gi];
          float bb = f[2 * i + 1] * rr * gq[2 * gi + 1];
          float2 cs = tab[r * 32 + gi];
          Qu[i] = pack2((a * cs.x - bb * cs.y) * SCALE_Q, (bb * cs.x + a * cs.y) * SCALE_Q);
        }
      }
      {
        const f16x8* src = (const f16x8*)(qkv + trow + 1024);
        float f[32];
#pragma unroll
        for (int c = 0; c < 4; ++c) {
          f16x8 v = src[c];
#pragma unroll
          for (int j = 0; j < 8; ++j) f[c * 8 + j] = (float)v[j];
        }
        float ssq = 0.f;
#pragma unroll
        for (int j = 0; j < 32; ++j) ssq += f[j] * f[j];
        ssq += __shfl_xor(ssq, 1);
        float rr = rsqrtf(ssq * (1.0f / 64.0f) + 1e-6f);
#pragma unroll
        for (int i = 0; i < 16; ++i) {
          int gi = hf * 16 + i;
          float a = f[2 * i] * rr * gk[2 * gi];
          float bb = f[2 * i + 1] * rr * gk[2 * gi + 1];
          float2 cs = tab[r * 32 + gi];
          Ku[i] = pack2(a * cs.x - bb * cs.y, bb * cs.x + a * cs.y);
        }
      }
      {
        const unsigned short* src = qkv + trow + 2048; // d = hf*32 ..
        union { uint4 q[4]; unsigned short us[32]; } tv;
#pragma unroll
        for (int c = 0; c < 4; ++c) tv.q[c] = ((const uint4*)src)[c];
#pragma unroll
        for (int j = 0; j < 32; ++j) Vw[(hf * 32 + j) * 40 + r] = tv.us[j];
      }
    } else {
#pragma unroll
      for (int i = 0; i < 16; ++i) { Qu[i] = 0; Ku[i] = 0; }
#pragma unroll
      for (int j = 0; j < 32; ++j) Vw[(hf * 32 + j) * 40 + r] = 0;
    }
  }
  __syncthreads();

  const int xr = (l15 & 3) ^ ((l15 >> 2) & 3);
  f16x8 aq[2][2], bk[2][2];
#pragma unroll
  for (int mt = 0; mt < 2; ++mt) {
    const char* base = (const char*)Qw + (mt * 16 + l15) * 144;
    aq[mt][0] = *(const f16x8a*)(base + quad * 16);
    aq[mt][1] = *(const f16x8a*)(base + 64 + quad * 16);
  }
#pragma unroll
  for (int ct = 0; ct < 2; ++ct) {
    const char* base = (const char*)Kw + (ct * 16 + l15) * 144;
    bk[ct][0] = *(const f16x8a*)(base + quad * 16);
    bk[ct][1] = *(const f16x8a*)(base + 64 + quad * 16);
  }
  f32x4 sc[2][2];
#pragma unroll
  for (int mt = 0; mt < 2; ++mt)
#pragma unroll
    for (int ct = 0; ct < 2; ++ct) {
      f32x4 z = (f32x4){0.f, 0.f, 0.f, 0.f};
      z = __builtin_amdgcn_mfma_f32_16x16x32_f16(aq[mt][0], bk[ct][0], z, 0, 0, 0);
      sc[mt][ct] = __builtin_amdgcn_mfma_f32_16x16x32_f16(aq[mt][1], bk[ct][1], z, 0, 0, 0);
    }
#pragma unroll
  for (int ct = 0; ct < 2; ++ct) {
    int col = ct * 16 + l15;
    if (col >= 24) {
#pragma unroll
      for (int mt = 0; mt < 2; ++mt)
#pragma unroll
        for (int rg = 0; rg < 4; ++rg) sc[mt][ct][rg] = -1e30f;
    }
  }
  float lr[2][4];
  unsigned short* Pw = Qw; // alias (Q frags already in regs)
#pragma unroll
  for (int mt = 0; mt < 2; ++mt)
#pragma unroll
    for (int rg = 0; rg < 4; ++rg) {
      float v0 = sc[mt][0][rg], v1 = sc[mt][1][rg];
      float cm = fmaxf(v0, v1);
      cm = fmaxf(cm, __shfl_xor(cm, 1));
      cm = fmaxf(cm, __shfl_xor(cm, 2));
      cm = fmaxf(cm, __shfl_xor(cm, 4));
      cm = fmaxf(cm, __shfl_xor(cm, 8));
      float p0 = exp2f(v0 - cm), p1 = exp2f(v1 - cm);
      float rs = p0 + p1;
      rs += __shfl_xor(rs, 1);
      rs += __shfl_xor(rs, 2);
      rs += __shfl_xor(rs, 4);
      rs += __shfl_xor(rs, 8);
      lr[mt][rg] = rs;
      int prow = mt * 16 + quad * 4 + rg;
      int xw = quad ^ rg;
      unsigned short* pb = Pw + prow * 32;
      pb[(((l15 >> 3) ^ xw) * 8) + (l15 & 7)] = f2h(p0);
      pb[(((2 + (l15 >> 3)) ^ xw) * 8) + (l15 & 7)] = f2h(p1);
    }
  __asm__ volatile("s_waitcnt lgkmcnt(0)" ::: "memory");
  f16x8 ap[2], bv[4];
#pragma unroll
  for (int mt = 0; mt < 2; ++mt)
    ap[mt] = *(const f16x8a*)((const char*)Pw + (mt * 16 + l15) * 64 + (quad ^ xr) * 16);
#pragma unroll
  for (int nt = 0; nt < 4; ++nt)
    bv[nt] = *(const f16x8a*)((const char*)Vw + (nt * 16 + l15) * 80 + quad * 16);
  f32x4 o[2][4];
#pragma unroll
  for (int mt = 0; mt < 2; ++mt)
#pragma unroll
    for (int nt = 0; nt < 4; ++nt) {
      o[mt][nt] = (f32x4){0.f, 0.f, 0.f, 0.f};
      o[mt][nt] = __builtin_amdgcn_mfma_f32_16x16x32_f16(ap[mt], bv[nt], o[mt][nt], 0, 0, 0);
    }
#pragma unroll
  for (int mt = 0; mt < 2; ++mt)
#pragma unroll
    for (int rg = 0; rg < 4; ++rg) {
      int s = mt * 16 + quad * 4 + rg;
      if (s < 24) {
        float inv = 1.0f / lr[mt][rg];
        unsigned short* dst = aout + ((size_t)(b * 24 + s) * 220 + p) * 1024 + h * 64;
#pragma unroll
        for (int nt = 0; nt < 4; ++nt) dst[nt * 16 + l15] = f2h(o[mt][nt][rg] * inv);
      }
    }
}

// ---------------------------------------------------------------- launch
extern "C" void kernel_launch(void* const* d_in, const int* in_sizes, int n_in,
                              void* d_out, int out_size, void* d_ws, size_t ws_size,
                              hipStream_t stream) {
  (void)in_sizes; (void)n_in; (void)out_size; (void)ws_size;
  const float* x = (const float*)d_in[0];
  const float* wsqkv = (const float*)d_in[1];
  const float* wsproj = (const float*)d_in[2];
  const float* bsproj = (const float*)d_in[3];
  const float* wtqkv = (const float*)d_in[4];
  const float* wtproj = (const float*)d_in[5];
  const float* btproj = (const float*)d_in[6];
  const float* sqg = (const float*)d_in[7];
  const float* skg = (const float*)d_in[8];
  const float* tqg = (const float*)d_in[9];
  const float* tkg = (const float*)d_in[10];

  char* ws = (char*)d_ws;
  size_t off = 0;
  auto alloc = [&](size_t bytes) {
    char* ptr = ws + off;
    off += (bytes + 255) & ~(size_t)255;
    return ptr;
  };
  unsigned short* xb = (unsigned short*)alloc((size_t)NTOK * 1024 * 2);  // also out_s
  unsigned short* qkvb = (unsigned short*)alloc((size_t)NTOK * 3072 * 2);
  unsigned short* aoutb = (unsigned short*)alloc((size_t)NTOK * 1024 * 2);
  unsigned short* wsqkvb = (unsigned short*)alloc((size_t)3072 * 1024 * 2);
  unsigned short* wsprojb = (unsigned short*)alloc((size_t)1024 * 1024 * 2);
  unsigned short* wtqkvb = (unsigned short*)alloc((size_t)3072 * 1024 * 2);
  unsigned short* wtprojb = (unsigned short*)alloc((size_t)1024 * 1024 * 2);
  float2* tabS = (float2*)alloc(220 * 32 * 8);
  float2* tabT = (float2*)alloc(24 * 32 * 8);

  dim3 blk(256);
  cast_kernel<<<21120, blk, 0, stream>>>(x, xb, 5406720);
  cast_kernel<<<3072, blk, 0, stream>>>(wsqkv, wsqkvb, 786432);
  cast_kernel<<<1024, blk, 0, stream>>>(wsproj, wsprojb, 262144);
  cast_kernel<<<3072, blk, 0, stream>>>(wtqkv, wtqkvb, 786432);
  cast_kernel<<<1024, blk, 0, stream>>>(wtproj, wtprojb, 262144);
  rope_table_kernel<<<31, blk, 0, stream>>>(tabS, tabT);

  // stage S
  gemm_bt<<<dim3(165, 24), blk, 0, stream>>>(xb, wsqkvb, nullptr, qkvb, NTOK, 3072, 1024, 0);
  attn_spatial<<<dim3(1536), blk, 0, stream>>>(qkvb, aoutb, tabS, sqg, skg);
  gemm_bt<<<dim3(165, 8), blk, 0, stream>>>(aoutb, wsprojb, bsproj, xb, NTOK, 1024, 1024, 1);
  // stage T (token layout unchanged; temporal attention strides by 220 tokens)
  gemm_bt<<<dim3(165, 24), blk, 0, stream>>>(xb, wtqkvb, nullptr, qkvb, NTOK, 3072, 1024, 0);
  attn_temporal<<<dim3(3520), blk, 0, stream>>>(qkvb, aoutb, tabT, tqg, tkg);
  gemm_bt<<<dim3(165, 8), blk, 0, stream>>>(aoutb, wtprojb, btproj, (float*)d_out, NTOK, 1024, 1024, 2);
}

// Round 3
// 969.059 us; speedup vs baseline: 1.1664x; 1.1664x over previous
//
#include <hip/hip_runtime.h>

typedef _Float16 f16;
typedef _Float16 f16x8 __attribute__((ext_vector_type(8)));
typedef f16x8 f16x8a __attribute__((may_alias));
typedef float f32x4 __attribute__((ext_vector_type(4)));

#define NTOK 21120          // 4 * 5280 tokens
#define SCALE_Q 0.18033688f // (1/8) * log2(e)

__device__ __forceinline__ void gll16(const void* g, void* l) {
  __builtin_amdgcn_global_load_lds(
      (const __attribute__((address_space(1))) unsigned int*)g,
      (__attribute__((address_space(3))) unsigned int*)l, 16, 0, 0);
}

__device__ __forceinline__ unsigned int pack2(float a, float b) {
  union { f16 h[2]; unsigned int u; } c;
  c.h[0] = (f16)a; c.h[1] = (f16)b;
  return c.u;
}
__device__ __forceinline__ unsigned short f2h(float a) {
  union { f16 h; unsigned short u; } c; c.h = (f16)a; return c.u;
}

// ---------------------------------------------------------------- casts
__global__ __launch_bounds__(256) void cast_kernel(
    const float* __restrict__ in, unsigned short* __restrict__ out, int n4) {
  int i = blockIdx.x * 256 + threadIdx.x;
  if (i >= n4) return;
  float4 v = ((const float4*)in)[i];
  uint2 o;
  o.x = pack2(v.x, v.y);
  o.y = pack2(v.z, v.w);
  ((uint2*)out)[i] = o;
}

// ---------------------------------------------------------------- rope tables
__global__ __launch_bounds__(256) void rope_table_kernel(float2* tabS, float2* tabT) {
  int t = blockIdx.x * 256 + threadIdx.x;
  const float lb = logf(10000.0f) * (1.0f / 32.0f);
  if (t < 220 * 32) {
    int s = t >> 5, i = t & 31;
    float theta = expf(-(float)i * lb);
    float ang = (float)s * theta;
    tabS[t] = make_float2(cosf(ang), sinf(ang));
  } else if (t < 220 * 32 + 24 * 32) {
    int u = t - 220 * 32;
    int s = u >> 5, i = u & 31;
    float theta = expf(-(float)i * lb);
    float ang = (float)s * theta;
    tabT[u] = make_float2(cosf(ang), sinf(ang));
  }
}

// ---------------------------------------------------------------- prep: in-place RMSNorm+gain+RoPE on Q,K planes
// mode 0: spatial (pos = t % 220, tabS), mode 1: temporal (pos = (t/220) % 24, tabT)
// Q additionally scaled by SCALE_Q (softmax scale * log2e folded in).
__global__ __launch_bounds__(256) void prep_qk(
    unsigned short* __restrict__ qkv, const float2* __restrict__ tab,
    const float* __restrict__ gq, const float* __restrict__ gk, int mode) {
  int u = blockIdx.x * 256 + threadIdx.x;
  int t = u >> 5, hh = u & 31;
  int h = hh >> 1, hf = hh & 1;
  int pos = (mode == 0) ? (t % 220) : ((t / 220) % 24);
  unsigned short* qp = qkv + (size_t)t * 3072 + h * 64 + hf * 32;
  unsigned short* kp = qp + 1024;
  float fq[32], fk[32];
  {
    const f16x8a* s0 = (const f16x8a*)qp;
    const f16x8a* s1 = (const f16x8a*)kp;
#pragma unroll
    for (int c = 0; c < 4; ++c) {
      f16x8 a = s0[c], b = s1[c];
#pragma unroll
      for (int j = 0; j < 8; ++j) { fq[c * 8 + j] = (float)a[j]; fk[c * 8 + j] = (float)b[j]; }
    }
  }
  float sq = 0.f, sk = 0.f;
#pragma unroll
  for (int j = 0; j < 32; ++j) { sq += fq[j] * fq[j]; sk += fk[j] * fk[j]; }
  sq += __shfl_xor(sq, 1);
  sk += __shfl_xor(sk, 1);
  float rq = rsqrtf(sq * (1.0f / 64.0f) + 1e-6f) * SCALE_Q;
  float rk = rsqrtf(sk * (1.0f / 64.0f) + 1e-6f);
  const float2* cs = tab + pos * 32 + hf * 16;
  const float2* g2q = (const float2*)gq + hf * 16;
  const float2* g2k = (const float2*)gk + hf * 16;
  unsigned int oq[16], ok[16];
#pragma unroll
  for (int i = 0; i < 16; ++i) {
    float2 c = cs[i];
    float2 gg = g2q[i];
    float a = fq[2 * i] * rq * gg.x, b = fq[2 * i + 1] * rq * gg.y;
    oq[i] = pack2(a * c.x - b * c.y, b * c.x + a * c.y);
    float2 gh = g2k[i];
    float ak = fk[2 * i] * rk * gh.x, bk = fk[2 * i + 1] * rk * gh.y;
    ok[i] = pack2(ak * c.x - bk * c.y, bk * c.x + ak * c.y);
  }
#pragma unroll
  for (int c = 0; c < 4; ++c) {
    ((uint4*)qp)[c] = ((const uint4*)oq)[c];
    ((uint4*)kp)[c] = ((const uint4*)ok)[c];
  }
}

// ---------------------------------------------------------------- GEMM  C = A * B^T (unchanged, known-good)
__global__ __launch_bounds__(256) void gemm_bt(
    const unsigned short* __restrict__ A, const unsigned short* __restrict__ B,
    const float* __restrict__ bias, void* __restrict__ C,
    int M, int N, int K, int outmode) {
  __shared__ __align__(16) unsigned short As[4096];
  __shared__ __align__(16) unsigned short Bs[4096];
  const int tid = threadIdx.x;
  const int w = tid >> 6, lane = tid & 63;
  const int l15 = lane & 15, quad = lane >> 4;
  const int wr = w >> 1, wc = w & 1;
  const int tm = blockIdx.x, tn = blockIdx.y;
  const int i4 = lane >> 2, pp = lane & 3;

  f32x4 acc[4][4];
#pragma unroll
  for (int a = 0; a < 4; ++a)
#pragma unroll
    for (int b = 0; b < 4; ++b) acc[a][b] = (f32x4){0.f, 0.f, 0.f, 0.f};

  int srow[2], scx[2];
#pragma unroll
  for (int c = 0; c < 2; ++c) {
    int r = (c * 4 + w) * 16 + i4;
    srow[c] = r;
    scx[c] = pp ^ ((r & 3) ^ ((r >> 2) & 3));
  }
  const int xr = (l15 & 3) ^ ((l15 >> 2) & 3);
  const size_t arow0 = (size_t)tm * 128;
  const size_t brow0 = (size_t)tn * 128;
  const int nk = K >> 5;

  for (int kt = 0; kt < nk; ++kt) {
    __syncthreads();
    const int kb = kt << 5;
#pragma unroll
    for (int c = 0; c < 2; ++c) {
      gll16(A + (arow0 + srow[c]) * K + kb + scx[c] * 8, (char*)As + (c * 4 + w) * 1024);
      gll16(B + (brow0 + srow[c]) * K + kb + scx[c] * 8, (char*)Bs + (c * 4 + w) * 1024);
    }
    __syncthreads();
    f16x8 af[4], bf[4];
#pragma unroll
    for (int mt = 0; mt < 4; ++mt) {
      int ra = wr * 64 + mt * 16 + l15;
      af[mt] = *(const f16x8a*)((const char*)As + ra * 64 + (quad ^ xr) * 16);
      int rb = wc * 64 + mt * 16 + l15;
      bf[mt] = *(const f16x8a*)((const char*)Bs + rb * 64 + (quad ^ xr) * 16);
    }
#pragma unroll
    for (int mt = 0; mt < 4; ++mt)
#pragma unroll
      for (int nt = 0; nt < 4; ++nt)
        acc[mt][nt] = __builtin_amdgcn_mfma_f32_16x16x32_f16(af[mt], bf[nt], acc[mt][nt], 0, 0, 0);
  }

  const int row0 = tm * 128 + wr * 64 + quad * 4;
  const int col0 = tn * 128 + wc * 64 + l15;
#pragma unroll
  for (int nt = 0; nt < 4; ++nt) {
    int cc = col0 + nt * 16;
    float bvv = 0.0f;
    if (outmode > 0) bvv = bias[cc];
#pragma unroll
    for (int mt = 0; mt < 4; ++mt) {
      int rr = row0 + mt * 16;
#pragma unroll
      for (int rg = 0; rg < 4; ++rg) {
        float v = acc[mt][nt][rg] + bvv;
        if (outmode == 2)
          ((float*)C)[(size_t)(rr + rg) * N + cc] = v;
        else
          ((unsigned short*)C)[(size_t)(rr + rg) * N + cc] = f2h(v);
      }
    }
  }
}

// ---------------------------------------------------------------- spatial attention (prep'd inputs)
// Block = (n,h). K staged to LDS in two halves via global_load_lds; V transposed
// once; Q fragments straight from global. No barriers inside chunk loops.
// No-max softmax: scores pre-scaled to log2 units, |s| <= ~11.5.
__global__ __launch_bounds__(256) void attn_spatial(
    const unsigned short* __restrict__ qkv, unsigned short* __restrict__ aout) {
  __shared__ __align__(16) unsigned short sh[30720]; // 61440 B
  unsigned short* Kls = sh;          // 128 rows x 64 halves (128B rows, chunk-swizzled)
  unsigned short* Vt = sh + 8192;    // 64 x 224 halves
  unsigned short* P = sh + 22528;    // 4 waves x 2048 halves
  const int tid = threadIdx.x;
  const int w = tid >> 6, lane = tid & 63;
  const int l15 = lane & 15, quad = lane >> 4;
  const int n = blockIdx.x >> 4, h = blockIdx.x & 15;
  const size_t tb = (size_t)n * 220;
  const unsigned short* qbase = qkv + tb * 3072 + h * 64;

  // Q fragments from global (already normed+roped+scaled)
  f16x8 aq[4][2];
#pragma unroll
  for (int mt = 0; mt < 4; ++mt) {
    int row = w * 64 + mt * 16 + l15;
    if (row > 219) row = 219;
#pragma unroll
    for (int c = 0; c < 2; ++c)
      aq[mt][c] = *(const f16x8a*)(qbase + (size_t)row * 3072 + c * 32 + quad * 8);
  }
  // V -> LDS transposed (once); zero-fill cols 220..223 (0 x NaN-garbage poisons MFMA)
  if (tid < 220) {
    const uint4* src = (const uint4*)(qbase + (size_t)tid * 3072 + 2048);
    uint4 vv[8];
#pragma unroll
    for (int c = 0; c < 8; ++c) vv[c] = src[c];
    const unsigned short* us = (const unsigned short*)vv;
#pragma unroll
    for (int d = 0; d < 64; ++d) Vt[d * 224 + tid] = us[d];
  } else if (tid < 224) {
#pragma unroll
    for (int d = 0; d < 64; ++d) Vt[d * 224 + tid] = 0;
  }

  float lsum[4][4];
  f32x4 o[4][4];
#pragma unroll
  for (int mt = 0; mt < 4; ++mt)
#pragma unroll
    for (int rg = 0; rg < 4; ++rg) lsum[mt][rg] = 0.f;
#pragma unroll
  for (int mt = 0; mt < 4; ++mt)
#pragma unroll
    for (int nt = 0; nt < 4; ++nt) o[mt][nt] = (f32x4){0.f, 0.f, 0.f, 0.f};

  const int xr = (l15 & 3) ^ ((l15 >> 2) & 3);
  unsigned short* Pw = P + w * 2048;

  for (int half = 0; half < 2; ++half) {
    const int k0 = half * 128;
    const int nslot = half ? 736 : 1024; // keys 128..219 in half 1
#pragma unroll
    for (int k = 0; k < 4; ++k) {
      int slot = k * 256 + tid;
      if (slot < nslot) {
        int rl = slot >> 3, c = slot & 7;
        gll16(qbase + (size_t)(k0 + rl) * 3072 + 1024 + ((c ^ (rl & 7)) * 8),
              (char*)Kls + k * 4096 + w * 1024);
      }
    }
    __syncthreads();
    const int nci = half ? 3 : 4;
    for (int ci = 0; ci < nci; ++ci) {
      const int cig = half * 4 + ci;
      f16x8 bk[2][2];
#pragma unroll
      for (int ct = 0; ct < 2; ++ct) {
        int rl = ci * 32 + ct * 16 + l15;
#pragma unroll
        for (int c = 0; c < 2; ++c)
          bk[ct][c] = *(const f16x8a*)((const char*)Kls + rl * 128 + (((quad + 4 * c) ^ (rl & 7)) * 16));
      }
      f32x4 sc[4][2];
#pragma unroll
      for (int mt = 0; mt < 4; ++mt)
#pragma unroll
        for (int ct = 0; ct < 2; ++ct) {
          f32x4 z = (f32x4){0.f, 0.f, 0.f, 0.f};
          z = __builtin_amdgcn_mfma_f32_16x16x32_f16(aq[mt][0], bk[ct][0], z, 0, 0, 0);
          sc[mt][ct] = __builtin_amdgcn_mfma_f32_16x16x32_f16(aq[mt][1], bk[ct][1], z, 0, 0, 0);
        }
      const int okk = (cig * 32 + 16 + l15) < 220; // ct=0 cols always valid (max 207)
#pragma unroll
      for (int mt = 0; mt < 4; ++mt)
#pragma unroll
        for (int rg = 0; rg < 4; ++rg) {
          float p0 = exp2f(sc[mt][0][rg]);
          float p1 = okk ? exp2f(sc[mt][1][rg]) : 0.0f;
          lsum[mt][rg] += p0 + p1;
          int xw = quad ^ rg;
          unsigned short* pb = Pw + (mt * 16 + quad * 4 + rg) * 32;
          pb[(((l15 >> 3) ^ xw) * 8) + (l15 & 7)] = f2h(p0);
          pb[(((2 + (l15 >> 3)) ^ xw) * 8) + (l15 & 7)] = f2h(p1);
        }
      __asm__ volatile("s_waitcnt lgkmcnt(0)" ::: "memory");
      f16x8 ap[4], bv[4];
#pragma unroll
      for (int mt = 0; mt < 4; ++mt)
        ap[mt] = *(const f16x8a*)((const char*)Pw + (mt * 16 + l15) * 64 + (quad ^ xr) * 16);
#pragma unroll
      for (int nt = 0; nt < 4; ++nt)
        bv[nt] = *(const f16x8a*)((const char*)Vt + (nt * 16 + l15) * 448 + cig * 64 + quad * 16);
#pragma unroll
      for (int mt = 0; mt < 4; ++mt)
#pragma unroll
        for (int nt = 0; nt < 4; ++nt)
          o[mt][nt] = __builtin_amdgcn_mfma_f32_16x16x32_f16(ap[mt], bv[nt], o[mt][nt], 0, 0, 0);
    }
    __syncthreads();
  }

  // epilogue: reduce lsum across l15, normalize, store
#pragma unroll
  for (int mt = 0; mt < 4; ++mt)
#pragma unroll
    for (int rg = 0; rg < 4; ++rg) {
      float l = lsum[mt][rg];
      l += __shfl_xor(l, 1);
      l += __shfl_xor(l, 2);
      l += __shfl_xor(l, 4);
      l += __shfl_xor(l, 8);
      int s = w * 64 + mt * 16 + quad * 4 + rg;
      if (s < 220) {
        float inv = 1.0f / l;
        unsigned short* dst = aout + (tb + s) * 1024 + h * 64;
#pragma unroll
        for (int nt = 0; nt < 4; ++nt) dst[nt * 16 + l15] = f2h(o[mt][nt][rg] * inv);
      }
    }
}

// ---------------------------------------------------------------- temporal attention (prep'd inputs)
// Block = (b, p, hquad); wave w = head hq*4+w; S=24 frames, one 32-key chunk.
__global__ __launch_bounds__(256) void attn_temporal(
    const unsigned short* __restrict__ qkv, unsigned short* __restrict__ aout) {
  __shared__ __align__(16) unsigned short sh[14336]; // 4 x (64x40 Vt + 32x32 P)
  const int tid = threadIdx.x;
  const int w = tid >> 6, lane = tid & 63;
  const int l15 = lane & 15, quad = lane >> 4;
  const int b = blockIdx.x / 880;
  const int rem = blockIdx.x % 880;
  const int p = rem >> 2, hq = rem & 3;
  const int h = hq * 4 + w;
  unsigned short* Vtw = sh + w * 2560;
  unsigned short* Pw = sh + 10240 + w * 1024;
  const unsigned short* base = qkv + ((size_t)(b * 24) * 220 + p) * 3072 + h * 64;
  const size_t fs = (size_t)220 * 3072;

  // V -> LDS transposed (per-wave); zero cols 24..31 (avoid 0 x garbage NaN)
  {
    int r = lane >> 1, hf = lane & 1;
    if (r < 24) {
      const uint4* src = (const uint4*)(base + r * fs + 2048 + hf * 32);
      uint4 vv[4];
#pragma unroll
      for (int c = 0; c < 4; ++c) vv[c] = src[c];
      const unsigned short* us = (const unsigned short*)vv;
#pragma unroll
      for (int j = 0; j < 32; ++j) Vtw[(hf * 32 + j) * 40 + r] = us[j];
    } else {
#pragma unroll
      for (int j = 0; j < 32; ++j) Vtw[(hf * 32 + j) * 40 + r] = 0;
    }
  }
  // Q, K fragments from global
  f16x8 aq[2][2], bk[2][2];
#pragma unroll
  for (int mt = 0; mt < 2; ++mt) {
    int row = mt * 16 + l15;
    if (row > 23) row = 23;
#pragma unroll
    for (int c = 0; c < 2; ++c)
      aq[mt][c] = *(const f16x8a*)(base + row * fs + c * 32 + quad * 8);
  }
#pragma unroll
  for (int ct = 0; ct < 2; ++ct) {
    int row = ct * 16 + l15;
    if (row > 23) row = 23;
#pragma unroll
    for (int c = 0; c < 2; ++c)
      bk[ct][c] = *(const f16x8a*)(base + row * fs + 1024 + c * 32 + quad * 8);
  }
  f32x4 sc[2][2];
#pragma unroll
  for (int mt = 0; mt < 2; ++mt)
#pragma unroll
    for (int ct = 0; ct < 2; ++ct) {
      f32x4 z = (f32x4){0.f, 0.f, 0.f, 0.f};
      z = __builtin_amdgcn_mfma_f32_16x16x32_f16(aq[mt][0], bk[ct][0], z, 0, 0, 0);
      sc[mt][ct] = __builtin_amdgcn_mfma_f32_16x16x32_f16(aq[mt][1], bk[ct][1], z, 0, 0, 0);
    }
  const int xr = (l15 & 3) ^ ((l15 >> 2) & 3);
  const int okk = l15 < 8; // cols 16+l15 valid iff < 24
  float lr[2][4];
#pragma unroll
  for (int mt = 0; mt < 2; ++mt)
#pragma unroll
    for (int rg = 0; rg < 4; ++rg) {
      float p0 = exp2f(sc[mt][0][rg]);
      float p1 = okk ? exp2f(sc[mt][1][rg]) : 0.0f;
      float rs = p0 + p1;
      rs += __shfl_xor(rs, 1);
      rs += __shfl_xor(rs, 2);
      rs += __shfl_xor(rs, 4);
      rs += __shfl_xor(rs, 8);
      lr[mt][rg] = rs;
      int xw = quad ^ rg;
      unsigned short* pb = Pw + (mt * 16 + quad * 4 + rg) * 32;
      pb[(((l15 >> 3) ^ xw) * 8) + (l15 & 7)] = f2h(p0);
      pb[(((2 + (l15 >> 3)) ^ xw) * 8) + (l15 & 7)] = f2h(p1);
    }
  __asm__ volatile("s_waitcnt lgkmcnt(0)" ::: "memory");
  f16x8 ap[2], bv[4];
#pragma unroll
  for (int mt = 0; mt < 2; ++mt)
    ap[mt] = *(const f16x8a*)((const char*)Pw + (mt * 16 + l15) * 64 + (quad ^ xr) * 16);
#pragma unroll
  for (int nt = 0; nt < 4; ++nt)
    bv[nt] = *(const f16x8a*)((const char*)Vtw + (nt * 16 + l15) * 80 + quad * 16);
  f32x4 o[2][4];
#pragma unroll
  for (int mt = 0; mt < 2; ++mt)
#pragma unroll
    for (int nt = 0; nt < 4; ++nt) {
      f32x4 z = (f32x4){0.f, 0.f, 0.f, 0.f};
      o[mt][nt] = __builtin_amdgcn_mfma_f32_16x16x32_f16(ap[mt], bv[nt], z, 0, 0, 0);
    }
#pragma unroll
  for (int mt = 0; mt < 2; ++mt)
#pragma unroll
    for (int rg = 0; rg < 4; ++rg) {
      int s = mt * 16 + quad * 4 + rg;
      if (s < 24) {
        float inv = 1.0f / lr[mt][rg];
        unsigned short* dst = aout + ((size_t)(b * 24 + s) * 220 + p) * 1024 + h * 64;
#pragma unroll
        for (int nt = 0; nt < 4; ++nt) dst[nt * 16 + l15] = f2h(o[mt][nt][rg] * inv);
      }
    }
}

// ---------------------------------------------------------------- launch
extern "C" void kernel_launch(void* const* d_in, const int* in_sizes, int n_in,
                              void* d_out, int out_size, void* d_ws, size_t ws_size,
                              hipStream_t stream) {
  (void)in_sizes; (void)n_in; (void)out_size; (void)ws_size;
  const float* x = (const float*)d_in[0];
  const float* wsqkv = (const float*)d_in[1];
  const float* wsproj = (const float*)d_in[2];
  const float* bsproj = (const float*)d_in[3];
  const float* wtqkv = (const float*)d_in[4];
  const float* wtproj = (const float*)d_in[5];
  const float* btproj = (const float*)d_in[6];
  const float* sqg = (const float*)d_in[7];
  const float* skg = (const float*)d_in[8];
  const float* tqg = (const float*)d_in[9];
  const float* tkg = (const float*)d_in[10];

  char* ws = (char*)d_ws;
  size_t off = 0;
  auto alloc = [&](size_t bytes) {
    char* ptr = ws + off;
    off += (bytes + 255) & ~(size_t)255;
    return ptr;
  };
  unsigned short* xb = (unsigned short*)alloc((size_t)NTOK * 1024 * 2);
  unsigned short* qkvb = (unsigned short*)alloc((size_t)NTOK * 3072 * 2);
  unsigned short* aoutb = (unsigned short*)alloc((size_t)NTOK * 1024 * 2);
  unsigned short* wsqkvb = (unsigned short*)alloc((size_t)3072 * 1024 * 2);
  unsigned short* wsprojb = (unsigned short*)alloc((size_t)1024 * 1024 * 2);
  unsigned short* wtqkvb = (unsigned short*)alloc((size_t)3072 * 1024 * 2);
  unsigned short* wtprojb = (unsigned short*)alloc((size_t)1024 * 1024 * 2);
  float2* tabS = (float2*)alloc(220 * 32 * 8);
  float2* tabT = (float2*)alloc(24 * 32 * 8);

  dim3 blk(256);
  cast_kernel<<<21120, blk, 0, stream>>>(x, xb, 5406720);
  cast_kernel<<<3072, blk, 0, stream>>>(wsqkv, wsqkvb, 786432);
  cast_kernel<<<1024, blk, 0, stream>>>(wsproj, wsprojb, 262144);
  cast_kernel<<<3072, blk, 0, stream>>>(wtqkv, wtqkvb, 786432);
  cast_kernel<<<1024, blk, 0, stream>>>(wtproj, wtprojb, 262144);
  rope_table_kernel<<<31, blk, 0, stream>>>(tabS, tabT);

  // stage S
  gemm_bt<<<dim3(165, 24), blk, 0, stream>>>(xb, wsqkvb, nullptr, qkvb, NTOK, 3072, 1024, 0);
  prep_qk<<<2640, blk, 0, stream>>>(qkvb, tabS, sqg, skg, 0);
  attn_spatial<<<dim3(1536), blk, 0, stream>>>(qkvb, aoutb);
  gemm_bt<<<dim3(165, 8), blk, 0, stream>>>(aoutb, wsprojb, bsproj, xb, NTOK, 1024, 1024, 1);
  // stage T
  gemm_bt<<<dim3(165, 24), blk, 0, stream>>>(xb, wtqkvb, nullptr, qkvb, NTOK, 3072, 1024, 0);
  prep_qk<<<2640, blk, 0, stream>>>(qkvb, tabT, tqg, tkg, 1);
  attn_temporal<<<dim3(3520), blk, 0, stream>>>(qkvb, aoutb);
  gemm_bt<<<dim3(165, 8), blk, 0, stream>>>(aoutb, wtprojb, btproj, (float*)d_out, NTOK, 1024, 1024, 2);
}

// Round 4
// 892.743 us; speedup vs baseline: 1.2661x; 1.0855x over previous
//
#include <hip/hip_runtime.h>

typedef _Float16 f16;
typedef _Float16 f16x8 __attribute__((ext_vector_type(8)));
typedef f16x8 f16x8a __attribute__((may_alias));
typedef float f32x4 __attribute__((ext_vector_type(4)));

#define NTOK 21120          // 4 * 5280 tokens
#define SCALE_Q 0.18033688f // (1/8) * log2(e)

__device__ __forceinline__ void gll16(const void* g, void* l) {
  __builtin_amdgcn_global_load_lds(
      (const __attribute__((address_space(1))) unsigned int*)g,
      (__attribute__((address_space(3))) unsigned int*)l, 16, 0, 0);
}

__device__ __forceinline__ unsigned int pack2(float a, float b) {
  union { f16 h[2]; unsigned int u; } c;
  c.h[0] = (f16)a; c.h[1] = (f16)b;
  return c.u;
}
__device__ __forceinline__ unsigned short f2h(float a) {
  union { f16 h; unsigned short u; } c; c.h = (f16)a; return c.u;
}

// ---------------------------------------------------------------- casts
__global__ __launch_bounds__(256) void cast_kernel(
    const float* __restrict__ in, unsigned short* __restrict__ out, int n4) {
  int i = blockIdx.x * 256 + threadIdx.x;
  if (i >= n4) return;
  float4 v = ((const float4*)in)[i];
  uint2 o;
  o.x = pack2(v.x, v.y);
  o.y = pack2(v.z, v.w);
  ((uint2*)out)[i] = o;
}

// ---------------------------------------------------------------- rope tables
__global__ __launch_bounds__(256) void rope_table_kernel(float2* tabS, float2* tabT) {
  int t = blockIdx.x * 256 + threadIdx.x;
  const float lb = logf(10000.0f) * (1.0f / 32.0f);
  if (t < 220 * 32) {
    int s = t >> 5, i = t & 31;
    float theta = expf(-(float)i * lb);
    float ang = (float)s * theta;
    tabS[t] = make_float2(cosf(ang), sinf(ang));
  } else if (t < 220 * 32 + 24 * 32) {
    int u = t - 220 * 32;
    int s = u >> 5, i = u & 31;
    float theta = expf(-(float)i * lb);
    float ang = (float)s * theta;
    tabT[u] = make_float2(cosf(ang), sinf(ang));
  }
}

// ---------------------------------------------------------------- prep: in-place RMSNorm+gain+RoPE on Q,K planes
__global__ __launch_bounds__(256) void prep_qk(
    unsigned short* __restrict__ qkv, const float2* __restrict__ tab,
    const float* __restrict__ gq, const float* __restrict__ gk, int mode) {
  int u = blockIdx.x * 256 + threadIdx.x;
  int t = u >> 5, hh = u & 31;
  int h = hh >> 1, hf = hh & 1;
  int pos = (mode == 0) ? (t % 220) : ((t / 220) % 24);
  unsigned short* qp = qkv + (size_t)t * 3072 + h * 64 + hf * 32;
  unsigned short* kp = qp + 1024;
  float fq[32], fk[32];
  {
    const f16x8a* s0 = (const f16x8a*)qp;
    const f16x8a* s1 = (const f16x8a*)kp;
#pragma unroll
    for (int c = 0; c < 4; ++c) {
      f16x8 a = s0[c], b = s1[c];
#pragma unroll
      for (int j = 0; j < 8; ++j) { fq[c * 8 + j] = (float)a[j]; fk[c * 8 + j] = (float)b[j]; }
    }
  }
  float sq = 0.f, sk = 0.f;
#pragma unroll
  for (int j = 0; j < 32; ++j) { sq += fq[j] * fq[j]; sk += fk[j] * fk[j]; }
  sq += __shfl_xor(sq, 1);
  sk += __shfl_xor(sk, 1);
  float rq = rsqrtf(sq * (1.0f / 64.0f) + 1e-6f) * SCALE_Q;
  float rk = rsqrtf(sk * (1.0f / 64.0f) + 1e-6f);
  const float2* cs = tab + pos * 32 + hf * 16;
  const float2* g2q = (const float2*)gq + hf * 16;
  const float2* g2k = (const float2*)gk + hf * 16;
  unsigned int oq[16], ok[16];
#pragma unroll
  for (int i = 0; i < 16; ++i) {
    float2 c = cs[i];
    float2 gg = g2q[i];
    float a = fq[2 * i] * rq * gg.x, b = fq[2 * i + 1] * rq * gg.y;
    oq[i] = pack2(a * c.x - b * c.y, b * c.x + a * c.y);
    float2 gh = g2k[i];
    float ak = fk[2 * i] * rk * gh.x, bk = fk[2 * i + 1] * rk * gh.y;
    ok[i] = pack2(ak * c.x - bk * c.y, bk * c.x + ak * c.y);
  }
#pragma unroll
  for (int c = 0; c < 4; ++c) {
    ((uint4*)qp)[c] = ((const uint4*)oq)[c];
    ((uint4*)kp)[c] = ((const uint4*)ok)[c];
  }
}

// ---------------------------------------------------------------- GEMM  C = A * B^T
// A[M,K], B[N,K] f16 K-contiguous. 1D grid with supertile swizzle (8 tm x ntn)
// for L2 reuse. Epilogue repacks C tile through LDS -> coalesced dwordx4 stores.
// outmode: 0 = f16, 1 = f16 + bias, 2 = f32 + bias.
__global__ __launch_bounds__(256) void gemm_bt(
    const unsigned short* __restrict__ A, const unsigned short* __restrict__ B,
    const float* __restrict__ bias, void* __restrict__ C,
    int M, int N, int K, int outmode) {
  __shared__ __align__(16) unsigned short sh[8704]; // 17408 B; staging uses 16384
  unsigned short* As = sh;
  unsigned short* Bs = sh + 4096;
  const int tid = threadIdx.x;
  const int w = tid >> 6, lane = tid & 63;
  const int l15 = lane & 15, quad = lane >> 4;
  const int wr = w >> 1, wc = w & 1;
  const int i4 = lane >> 2, pp = lane & 3;

  // supertile swizzle: groups of 8 tm x ntn blocks
  const int ntn = N >> 7;
  const int stride = ntn << 3;
  const int g = blockIdx.x / stride, r = blockIdx.x % stride;
  const int tn = r % ntn, tm = g * 8 + r / ntn;

  f32x4 acc[4][4];
#pragma unroll
  for (int a = 0; a < 4; ++a)
#pragma unroll
    for (int b = 0; b < 4; ++b) acc[a][b] = (f32x4){0.f, 0.f, 0.f, 0.f};

  int srow[2], scx[2];
#pragma unroll
  for (int c = 0; c < 2; ++c) {
    int rr = (c * 4 + w) * 16 + i4;
    srow[c] = rr;
    scx[c] = pp ^ ((rr & 3) ^ ((rr >> 2) & 3));
  }
  const int xr = (l15 & 3) ^ ((l15 >> 2) & 3);
  const size_t arow0 = (size_t)tm * 128;
  const size_t brow0 = (size_t)tn * 128;
  const int nk = K >> 5;

  for (int kt = 0; kt < nk; ++kt) {
    __syncthreads();
    const int kb = kt << 5;
#pragma unroll
    for (int c = 0; c < 2; ++c) {
      gll16(A + (arow0 + srow[c]) * K + kb + scx[c] * 8, (char*)As + (c * 4 + w) * 1024);
      gll16(B + (brow0 + srow[c]) * K + kb + scx[c] * 8, (char*)Bs + (c * 4 + w) * 1024);
    }
    __syncthreads();
    f16x8 af[4], bf[4];
#pragma unroll
    for (int mt = 0; mt < 4; ++mt) {
      int ra = wr * 64 + mt * 16 + l15;
      af[mt] = *(const f16x8a*)((const char*)As + ra * 64 + (quad ^ xr) * 16);
      int rb = wc * 64 + mt * 16 + l15;
      bf[mt] = *(const f16x8a*)((const char*)Bs + rb * 64 + (quad ^ xr) * 16);
    }
#pragma unroll
    for (int mt = 0; mt < 4; ++mt)
#pragma unroll
      for (int nt = 0; nt < 4; ++nt)
        acc[mt][nt] = __builtin_amdgcn_mfma_f32_16x16x32_f16(af[mt], bf[nt], acc[mt][nt], 0, 0, 0);
  }

  float bv[4];
#pragma unroll
  for (int nt = 0; nt < 4; ++nt) bv[nt] = 0.f;
  if (outmode > 0) {
#pragma unroll
    for (int nt = 0; nt < 4; ++nt) bv[nt] = bias[tn * 128 + wc * 64 + nt * 16 + l15];
  }

  if (outmode == 2) {
    const int row0 = tm * 128 + wr * 64 + quad * 4;
    const int col0 = tn * 128 + wc * 64 + l15;
#pragma unroll
    for (int nt = 0; nt < 4; ++nt) {
      int cc = col0 + nt * 16;
#pragma unroll
      for (int mt = 0; mt < 4; ++mt) {
        int rr = row0 + mt * 16;
#pragma unroll
        for (int rg = 0; rg < 4; ++rg)
          ((float*)C)[(size_t)(rr + rg) * N + cc] = acc[mt][nt][rg] + bv[nt];
      }
    }
    return;
  }

  // f16 epilogue: 2 passes through LDS (64 rows x 128 cols, stride 136 shorts)
  unsigned short* Cs = (unsigned short*)C;
#pragma unroll
  for (int p = 0; p < 2; ++p) {
    __syncthreads();
#pragma unroll
    for (int mi = 0; mi < 2; ++mi) {
      int mt = p * 2 + mi;
      int rl = wr * 32 + mi * 16 + quad * 4;
#pragma unroll
      for (int nt = 0; nt < 4; ++nt) {
        int cl = wc * 64 + nt * 16 + l15;
#pragma unroll
        for (int rg = 0; rg < 4; ++rg)
          sh[(rl + rg) * 136 + cl] = f2h(acc[mt][nt][rg] + bv[nt]);
      }
    }
    __syncthreads();
#pragma unroll
    for (int c = 0; c < 4; ++c) {
      int rl = c * 16 + (tid >> 4), cx = tid & 15;
      int grow = tm * 128 + ((rl >> 5) << 6) + p * 32 + (rl & 31);
      uint4 v = *(const uint4*)&sh[rl * 136 + cx * 8];
      *(uint4*)&Cs[(size_t)grow * N + tn * 128 + cx * 8] = v;
    }
  }
}

// ---------------------------------------------------------------- spatial attention (prep'd inputs)
__global__ __launch_bounds__(256) void attn_spatial(
    const unsigned short* __restrict__ qkv, unsigned short* __restrict__ aout) {
  __shared__ __align__(16) unsigned short sh[30720]; // 61440 B
  unsigned short* Kls = sh;          // 128 rows x 64 halves (128B rows, chunk-swizzled)
  unsigned short* Vt = sh + 8192;    // 64 x 224 halves
  unsigned short* P = sh + 22528;    // 4 waves x 2048 halves
  const int tid = threadIdx.x;
  const int w = tid >> 6, lane = tid & 63;
  const int l15 = lane & 15, quad = lane >> 4;
  const int n = blockIdx.x >> 4, h = blockIdx.x & 15;
  const size_t tb = (size_t)n * 220;
  const unsigned short* qbase = qkv + tb * 3072 + h * 64;

  f16x8 aq[4][2];
#pragma unroll
  for (int mt = 0; mt < 4; ++mt) {
    int row = w * 64 + mt * 16 + l15;
    if (row > 219) row = 219;
#pragma unroll
    for (int c = 0; c < 2; ++c)
      aq[mt][c] = *(const f16x8a*)(qbase + (size_t)row * 3072 + c * 32 + quad * 8);
  }
  if (tid < 220) {
    const uint4* src = (const uint4*)(qbase + (size_t)tid * 3072 + 2048);
    uint4 vv[8];
#pragma unroll
    for (int c = 0; c < 8; ++c) vv[c] = src[c];
    const unsigned short* us = (const unsigned short*)vv;
#pragma unroll
    for (int d = 0; d < 64; ++d) Vt[d * 224 + tid] = us[d];
  } else if (tid < 224) {
#pragma unroll
    for (int d = 0; d < 64; ++d) Vt[d * 224 + tid] = 0;
  }

  float lsum[4][4];
  f32x4 o[4][4];
#pragma unroll
  for (int mt = 0; mt < 4; ++mt)
#pragma unroll
    for (int rg = 0; rg < 4; ++rg) lsum[mt][rg] = 0.f;
#pragma unroll
  for (int mt = 0; mt < 4; ++mt)
#pragma unroll
    for (int nt = 0; nt < 4; ++nt) o[mt][nt] = (f32x4){0.f, 0.f, 0.f, 0.f};

  const int xr = (l15 & 3) ^ ((l15 >> 2) & 3);
  unsigned short* Pw = P + w * 2048;

  for (int half = 0; half < 2; ++half) {
    const int k0 = half * 128;
    const int nslot = half ? 736 : 1024;
#pragma unroll
    for (int k = 0; k < 4; ++k) {
      int slot = k * 256 + tid;
      if (slot < nslot) {
        int rl = slot >> 3, c = slot & 7;
        gll16(qbase + (size_t)(k0 + rl) * 3072 + 1024 + ((c ^ (rl & 7)) * 8),
              (char*)Kls + k * 4096 + w * 1024);
      }
    }
    __syncthreads();
    const int nci = half ? 3 : 4;
    for (int ci = 0; ci < nci; ++ci) {
      const int cig = half * 4 + ci;
      f16x8 bk[2][2];
#pragma unroll
      for (int ct = 0; ct < 2; ++ct) {
        int rl = ci * 32 + ct * 16 + l15;
#pragma unroll
        for (int c = 0; c < 2; ++c)
          bk[ct][c] = *(const f16x8a*)((const char*)Kls + rl * 128 + (((quad + 4 * c) ^ (rl & 7)) * 16));
      }
      f32x4 sc[4][2];
#pragma unroll
      for (int mt = 0; mt < 4; ++mt)
#pragma unroll
        for (int ct = 0; ct < 2; ++ct) {
          f32x4 z = (f32x4){0.f, 0.f, 0.f, 0.f};
          z = __builtin_amdgcn_mfma_f32_16x16x32_f16(aq[mt][0], bk[ct][0], z, 0, 0, 0);
          sc[mt][ct] = __builtin_amdgcn_mfma_f32_16x16x32_f16(aq[mt][1], bk[ct][1], z, 0, 0, 0);
        }
      const int okk = (cig * 32 + 16 + l15) < 220;
#pragma unroll
      for (int mt = 0; mt < 4; ++mt)
#pragma unroll
        for (int rg = 0; rg < 4; ++rg) {
          float p0 = exp2f(sc[mt][0][rg]);
          float p1 = okk ? exp2f(sc[mt][1][rg]) : 0.0f;
          lsum[mt][rg] += p0 + p1;
          int xw = quad ^ rg;
          unsigned short* pb = Pw + (mt * 16 + quad * 4 + rg) * 32;
          pb[(((l15 >> 3) ^ xw) * 8) + (l15 & 7)] = f2h(p0);
          pb[(((2 + (l15 >> 3)) ^ xw) * 8) + (l15 & 7)] = f2h(p1);
        }
      __asm__ volatile("s_waitcnt lgkmcnt(0)" ::: "memory");
      f16x8 ap[4], bv[4];
#pragma unroll
      for (int mt = 0; mt < 4; ++mt)
        ap[mt] = *(const f16x8a*)((const char*)Pw + (mt * 16 + l15) * 64 + (quad ^ xr) * 16);
#pragma unroll
      for (int nt = 0; nt < 4; ++nt)
        bv[nt] = *(const f16x8a*)((const char*)Vt + (nt * 16 + l15) * 448 + cig * 64 + quad * 16);
#pragma unroll
      for (int mt = 0; mt < 4; ++mt)
#pragma unroll
        for (int nt = 0; nt < 4; ++nt)
          o[mt][nt] = __builtin_amdgcn_mfma_f32_16x16x32_f16(ap[mt], bv[nt], o[mt][nt], 0, 0, 0);
    }
    __syncthreads();
  }

#pragma unroll
  for (int mt = 0; mt < 4; ++mt)
#pragma unroll
    for (int rg = 0; rg < 4; ++rg) {
      float l = lsum[mt][rg];
      l += __shfl_xor(l, 1);
      l += __shfl_xor(l, 2);
      l += __shfl_xor(l, 4);
      l += __shfl_xor(l, 8);
      int s = w * 64 + mt * 16 + quad * 4 + rg;
      if (s < 220) {
        float inv = 1.0f / l;
        unsigned short* dst = aout + (tb + s) * 1024 + h * 64;
#pragma unroll
        for (int nt = 0; nt < 4; ++nt) dst[nt * 16 + l15] = f2h(o[mt][nt][rg] * inv);
      }
    }
}

// ---------------------------------------------------------------- temporal attention (prep'd inputs)
__global__ __launch_bounds__(256) void attn_temporal(
    const unsigned short* __restrict__ qkv, unsigned short* __restrict__ aout) {
  __shared__ __align__(16) unsigned short sh[14336];
  const int tid = threadIdx.x;
  const int w = tid >> 6, lane = tid & 63;
  const int l15 = lane & 15, quad = lane >> 4;
  const int b = blockIdx.x / 880;
  const int rem = blockIdx.x % 880;
  const int p = rem >> 2, hq = rem & 3;
  const int h = hq * 4 + w;
  unsigned short* Vtw = sh + w * 2560;
  unsigned short* Pw = sh + 10240 + w * 1024;
  const unsigned short* base = qkv + ((size_t)(b * 24) * 220 + p) * 3072 + h * 64;
  const size_t fs = (size_t)220 * 3072;

  {
    int r = lane >> 1, hf = lane & 1;
    if (r < 24) {
      const uint4* src = (const uint4*)(base + r * fs + 2048 + hf * 32);
      uint4 vv[4];
#pragma unroll
      for (int c = 0; c < 4; ++c) vv[c] = src[c];
      const unsigned short* us = (const unsigned short*)vv;
#pragma unroll
      for (int j = 0; j < 32; ++j) Vtw[(hf * 32 + j) * 40 + r] = us[j];
    } else {
#pragma unroll
      for (int j = 0; j < 32; ++j) Vtw[(hf * 32 + j) * 40 + r] = 0;
    }
  }
  f16x8 aq[2][2], bk[2][2];
#pragma unroll
  for (int mt = 0; mt < 2; ++mt) {
    int row = mt * 16 + l15;
    if (row > 23) row = 23;
#pragma unroll
    for (int c = 0; c < 2; ++c)
      aq[mt][c] = *(const f16x8a*)(base + row * fs + c * 32 + quad * 8);
  }
#pragma unroll
  for (int ct = 0; ct < 2; ++ct) {
    int row = ct * 16 + l15;
    if (row > 23) row = 23;
#pragma unroll
    for (int c = 0; c < 2; ++c)
      bk[ct][c] = *(const f16x8a*)(base + row * fs + 1024 + c * 32 + quad * 8);
  }
  f32x4 sc[2][2];
#pragma unroll
  for (int mt = 0; mt < 2; ++mt)
#pragma unroll
    for (int ct = 0; ct < 2; ++ct) {
      f32x4 z = (f32x4){0.f, 0.f, 0.f, 0.f};
      z = __builtin_amdgcn_mfma_f32_16x16x32_f16(aq[mt][0], bk[ct][0], z, 0, 0, 0);
      sc[mt][ct] = __builtin_amdgcn_mfma_f32_16x16x32_f16(aq[mt][1], bk[ct][1], z, 0, 0, 0);
    }
  const int xr = (l15 & 3) ^ ((l15 >> 2) & 3);
  const int okk = l15 < 8;
  float lr[2][4];
#pragma unroll
  for (int mt = 0; mt < 2; ++mt)
#pragma unroll
    for (int rg = 0; rg < 4; ++rg) {
      float p0 = exp2f(sc[mt][0][rg]);
      float p1 = okk ? exp2f(sc[mt][1][rg]) : 0.0f;
      float rs = p0 + p1;
      rs += __shfl_xor(rs, 1);
      rs += __shfl_xor(rs, 2);
      rs += __shfl_xor(rs, 4);
      rs += __shfl_xor(rs, 8);
      lr[mt][rg] = rs;
      int xw = quad ^ rg;
      unsigned short* pb = Pw + (mt * 16 + quad * 4 + rg) * 32;
      pb[(((l15 >> 3) ^ xw) * 8) + (l15 & 7)] = f2h(p0);
      pb[(((2 + (l15 >> 3)) ^ xw) * 8) + (l15 & 7)] = f2h(p1);
    }
  __asm__ volatile("s_waitcnt lgkmcnt(0)" ::: "memory");
  f16x8 ap[2], bv[4];
#pragma unroll
  for (int mt = 0; mt < 2; ++mt)
    ap[mt] = *(const f16x8a*)((const char*)Pw + (mt * 16 + l15) * 64 + (quad ^ xr) * 16);
#pragma unroll
  for (int nt = 0; nt < 4; ++nt)
    bv[nt] = *(const f16x8a*)((const char*)Vtw + (nt * 16 + l15) * 80 + quad * 16);
  f32x4 o[2][4];
#pragma unroll
  for (int mt = 0; mt < 2; ++mt)
#pragma unroll
    for (int nt = 0; nt < 4; ++nt) {
      f32x4 z = (f32x4){0.f, 0.f, 0.f, 0.f};
      o[mt][nt] = __builtin_amdgcn_mfma_f32_16x16x32_f16(ap[mt], bv[nt], z, 0, 0, 0);
    }
#pragma unroll
  for (int mt = 0; mt < 2; ++mt)
#pragma unroll
    for (int rg = 0; rg < 4; ++rg) {
      int s = mt * 16 + quad * 4 + rg;
      if (s < 24) {
        float inv = 1.0f / lr[mt][rg];
        unsigned short* dst = aout + ((size_t)(b * 24 + s) * 220 + p) * 1024 + h * 64;
#pragma unroll
        for (int nt = 0; nt < 4; ++nt) dst[nt * 16 + l15] = f2h(o[mt][nt][rg] * inv);
      }
    }
}

// ---------------------------------------------------------------- launch
extern "C" void kernel_launch(void* const* d_in, const int* in_sizes, int n_in,
                              void* d_out, int out_size, void* d_ws, size_t ws_size,
                              hipStream_t stream) {
  (void)in_sizes; (void)n_in; (void)out_size; (void)ws_size;
  const float* x = (const float*)d_in[0];
  const float* wsqkv = (const float*)d_in[1];
  const float* wsproj = (const float*)d_in[2];
  const float* bsproj = (const float*)d_in[3];
  const float* wtqkv = (const float*)d_in[4];
  const float* wtproj = (const float*)d_in[5];
  const float* btproj = (const float*)d_in[6];
  const float* sqg = (const float*)d_in[7];
  const float* skg = (const float*)d_in[8];
  const float* tqg = (const float*)d_in[9];
  const float* tkg = (const float*)d_in[10];

  char* ws = (char*)d_ws;
  size_t off = 0;
  auto alloc = [&](size_t bytes) {
    char* ptr = ws + off;
    off += (bytes + 255) & ~(size_t)255;
    return ptr;
  };
  unsigned short* xb = (unsigned short*)alloc((size_t)NTOK * 1024 * 2);
  unsigned short* qkvb = (unsigned short*)alloc((size_t)NTOK * 3072 * 2);
  unsigned short* aoutb = (unsigned short*)alloc((size_t)NTOK * 1024 * 2);
  unsigned short* wsqkvb = (unsigned short*)alloc((size_t)3072 * 1024 * 2);
  unsigned short* wsprojb = (unsigned short*)alloc((size_t)1024 * 1024 * 2);
  unsigned short* wtqkvb = (unsigned short*)alloc((size_t)3072 * 1024 * 2);
  unsigned short* wtprojb = (unsigned short*)alloc((size_t)1024 * 1024 * 2);
  float2* tabS = (float2*)alloc(220 * 32 * 8);
  float2* tabT = (float2*)alloc(24 * 32 * 8);

  dim3 blk(256);
  cast_kernel<<<21120, blk, 0, stream>>>(x, xb, 5406720);
  cast_kernel<<<3072, blk, 0, stream>>>(wsqkv, wsqkvb, 786432);
  cast_kernel<<<1024, blk, 0, stream>>>(wsproj, wsprojb, 262144);
  cast_kernel<<<3072, blk, 0, stream>>>(wtqkv, wtqkvb, 786432);
  cast_kernel<<<1024, blk, 0, stream>>>(wtproj, wtprojb, 262144);
  rope_table_kernel<<<31, blk, 0, stream>>>(tabS, tabT);

  // stage S
  gemm_bt<<<dim3(165 * 24), blk, 0, stream>>>(xb, wsqkvb, nullptr, qkvb, NTOK, 3072, 1024, 0);
  prep_qk<<<2640, blk, 0, stream>>>(qkvb, tabS, sqg, skg, 0);
  attn_spatial<<<dim3(1536), blk, 0, stream>>>(qkvb, aoutb);
  gemm_bt<<<dim3(165 * 8), blk, 0, stream>>>(aoutb, wsprojb, bsproj, xb, NTOK, 1024, 1024, 1);
  // stage T
  gemm_bt<<<dim3(165 * 24), blk, 0, stream>>>(xb, wtqkvb, nullptr, qkvb, NTOK, 3072, 1024, 0);
  prep_qk<<<2640, blk, 0, stream>>>(qkvb, tabT, tqg, tkg, 1);
  attn_temporal<<<dim3(3520), blk, 0, stream>>>(qkvb, aoutb);
  gemm_bt<<<dim3(165 * 8), blk, 0, stream>>>(aoutb, wtprojb, btproj, (float*)d_out, NTOK, 1024, 1024, 2);
}

// Round 5
// 842.860 us; speedup vs baseline: 1.3410x; 1.0592x over previous
//
#include <hip/hip_runtime.h>

typedef _Float16 f16;
typedef _Float16 f16x8 __attribute__((ext_vector_type(8)));
typedef f16x8 f16x8a __attribute__((may_alias));
typedef float f32x4 __attribute__((ext_vector_type(4)));

#define NTOK 21120          // 4 * 5280 tokens
#define SCALE_Q 0.18033688f // (1/8) * log2(e)

__device__ __forceinline__ void gll16(const void* g, void* l) {
  __builtin_amdgcn_global_load_lds(
      (const __attribute__((address_space(1))) unsigned int*)g,
      (__attribute__((address_space(3))) unsigned int*)l, 16, 0, 0);
}

__device__ __forceinline__ unsigned int pack2(float a, float b) {
  union { f16 h[2]; unsigned int u; } c;
  c.h[0] = (f16)a; c.h[1] = (f16)b;
  return c.u;
}
__device__ __forceinline__ unsigned short f2h(float a) {
  union { f16 h; unsigned short u; } c; c.h = (f16)a; return c.u;
}

// ---------------------------------------------------------------- casts
__global__ __launch_bounds__(256) void cast_kernel(
    const float* __restrict__ in, unsigned short* __restrict__ out, int n4) {
  int i = blockIdx.x * 256 + threadIdx.x;
  if (i >= n4) return;
  float4 v = ((const float4*)in)[i];
  uint2 o;
  o.x = pack2(v.x, v.y);
  o.y = pack2(v.z, v.w);
  ((uint2*)out)[i] = o;
}

// ---------------------------------------------------------------- rope tables
__global__ __launch_bounds__(256) void rope_table_kernel(float2* tabS, float2* tabT) {
  int t = blockIdx.x * 256 + threadIdx.x;
  const float lb = logf(10000.0f) * (1.0f / 32.0f);
  if (t < 220 * 32) {
    int s = t >> 5, i = t & 31;
    float theta = expf(-(float)i * lb);
    float ang = (float)s * theta;
    tabS[t] = make_float2(cosf(ang), sinf(ang));
  } else if (t < 220 * 32 + 24 * 32) {
    int u = t - 220 * 32;
    int s = u >> 5, i = u & 31;
    float theta = expf(-(float)i * lb);
    float ang = (float)s * theta;
    tabT[u] = make_float2(cosf(ang), sinf(ang));
  }
}

// ---------------------------------------------------------------- GEMM  C = A * B^T
// A[M,K], B[N,K] f16 K-contiguous. BK=64 (32 KB LDS), 1D grid supertile swizzle.
// outmode: 0 = f16, 1 = f16 + bias, 2 = f32 + bias (coalesced via LDS),
//          3 = fused QKV prep: tn<8 -> Q (rmsnorm+gain+rope+SCALE_Q),
//              tn in [8,16) -> K (rmsnorm+gain+rope), tn>=16 -> V plain f16.
__global__ __launch_bounds__(256) void gemm_bt(
    const unsigned short* __restrict__ A, const unsigned short* __restrict__ B,
    const float* __restrict__ bias, void* __restrict__ C,
    int M, int N, int K, int outmode,
    const float2* __restrict__ tab, const float* __restrict__ gq,
    const float* __restrict__ gk, int mode) {
  __shared__ __align__(16) unsigned short sh[16384]; // 32 KB: staging / epilogue
  unsigned short* As = sh;        // 128 rows x 64 f16 (128B rows, chunk-swizzled)
  unsigned short* Bs = sh + 8192;
  const int tid = threadIdx.x;
  const int w = tid >> 6, lane = tid & 63;
  const int l15 = lane & 15, quad = lane >> 4;
  const int wr = w >> 1, wc = w & 1;

  // supertile swizzle: groups of 8 tm x ntn blocks
  const int ntn = N >> 7;
  const int stride = ntn << 3;
  const int g = blockIdx.x / stride, r = blockIdx.x % stride;
  const int tn = r % ntn, tm = g * 8 + r / ntn;

  f32x4 acc[4][4];
#pragma unroll
  for (int a = 0; a < 4; ++a)
#pragma unroll
    for (int b = 0; b < 4; ++b) acc[a][b] = (f32x4){0.f, 0.f, 0.f, 0.f};

  const int srow = tid >> 3;      // row-in-32 per staging round
  const int schk = tid & 7;       // chunk slot 0..7
  const size_t arow0 = (size_t)tm * 128;
  const size_t brow0 = (size_t)tn * 128;
  const int nk = K >> 6;

  for (int kt = 0; kt < nk; ++kt) {
    __syncthreads();
    const int kb = kt << 6;
#pragma unroll
    for (int rd = 0; rd < 4; ++rd) {
      int row = rd * 32 + srow;
      int sc = (schk ^ (row & 7)) * 8;
      gll16(A + (arow0 + row) * K + kb + sc, (char*)As + rd * 4096 + tid * 16);
      gll16(B + (brow0 + row) * K + kb + sc, (char*)Bs + rd * 4096 + tid * 16);
    }
    __syncthreads();
#pragma unroll
    for (int kk = 0; kk < 2; ++kk) {
      f16x8 af[4], bf[4];
#pragma unroll
      for (int mt = 0; mt < 4; ++mt) {
        int ra = wr * 64 + mt * 16 + l15;
        af[mt] = *(const f16x8a*)((const char*)As + ra * 128 + (((kk * 4 + quad) ^ (ra & 7)) * 16));
        int rb = wc * 64 + mt * 16 + l15;
        bf[mt] = *(const f16x8a*)((const char*)Bs + rb * 128 + (((kk * 4 + quad) ^ (rb & 7)) * 16));
      }
#pragma unroll
      for (int mt = 0; mt < 4; ++mt)
#pragma unroll
        for (int nt = 0; nt < 4; ++nt)
          acc[mt][nt] = __builtin_amdgcn_mfma_f32_16x16x32_f16(af[mt], bf[nt], acc[mt][nt], 0, 0, 0);
    }
  }

  float bv[4];
#pragma unroll
  for (int nt = 0; nt < 4; ++nt) bv[nt] = 0.f;
  if (outmode == 1 || outmode == 2) {
#pragma unroll
    for (int nt = 0; nt < 4; ++nt) bv[nt] = bias[tn * 128 + wc * 64 + nt * 16 + l15];
  }

  if (outmode == 2) {
    // f32 + bias, coalesced: per-mt pass through LDS (32 rows x 128 f32, stride 132)
    float* shf = (float*)sh;
#pragma unroll
    for (int mt = 0; mt < 4; ++mt) {
      __syncthreads();
#pragma unroll
      for (int nt = 0; nt < 4; ++nt)
#pragma unroll
        for (int rg = 0; rg < 4; ++rg)
          shf[(wr * 16 + quad * 4 + rg) * 132 + wc * 64 + nt * 16 + l15] = acc[mt][nt][rg] + bv[nt];
      __syncthreads();
      int l = tid >> 3, c8 = tid & 7;
      int grow = tm * 128 + ((l >> 4) << 6) + mt * 16 + (l & 15);
      float4* dst = (float4*)((float*)C + (size_t)grow * N + tn * 128 + c8 * 16);
      const float4* srcp = (const float4*)(shf + l * 132 + c8 * 16);
#pragma unroll
      for (int c = 0; c < 4; ++c) dst[c] = srcp[c];
    }
    return;
  }

  if (outmode == 3 && tn < 16) {
    // fused RMSNorm + gain + RoPE epilogue for Q/K tiles (2 heads per tile)
    const int qtile = tn < 8;
    const float* gg = qtile ? gq : gk;
    float* shf = (float*)sh;
    const int sub = tid & 3, pr = tid >> 2;
    const int l = pr >> 1, head = pr & 1;
#pragma unroll
    for (int mt = 0; mt < 4; ++mt) {
      __syncthreads();
#pragma unroll
      for (int nt = 0; nt < 4; ++nt)
#pragma unroll
        for (int rg = 0; rg < 4; ++rg)
          shf[(wr * 16 + quad * 4 + rg) * 132 + wc * 64 + nt * 16 + l15] = acc[mt][nt][rg];
      __syncthreads();
      int grow = tm * 128 + ((l >> 4) << 6) + mt * 16 + (l & 15);
      int pos = (mode == 0) ? (grow % 220) : ((grow / 220) % 24);
      float v[16];
      const float4* vsrc = (const float4*)(shf + l * 132 + head * 64 + sub * 16);
#pragma unroll
      for (int c = 0; c < 4; ++c) {
        float4 t4 = vsrc[c];
        v[c * 4 + 0] = t4.x; v[c * 4 + 1] = t4.y; v[c * 4 + 2] = t4.z; v[c * 4 + 3] = t4.w;
      }
      float ssq = 0.f;
#pragma unroll
      for (int j = 0; j < 16; ++j) ssq += v[j] * v[j];
      ssq += __shfl_xor(ssq, 1);
      ssq += __shfl_xor(ssq, 2);
      float rr = rsqrtf(ssq * (1.0f / 64.0f) + 1e-6f);
      if (qtile) rr *= SCALE_Q;
      const float2* cs = tab + pos * 32 + sub * 8;
      const float2* g2 = (const float2*)gg + sub * 8;
      unsigned int o8[8];
#pragma unroll
      for (int jj = 0; jj < 8; ++jj) {
        float2 c = cs[jj], gp = g2[jj];
        float a = v[2 * jj] * rr * gp.x, b = v[2 * jj + 1] * rr * gp.y;
        o8[jj] = pack2(a * c.x - b * c.y, b * c.x + a * c.y);
      }
      unsigned short* dstp = (unsigned short*)C + (size_t)grow * N + tn * 128 + head * 64 + sub * 16;
      ((uint4*)dstp)[0] = ((const uint4*)o8)[0];
      ((uint4*)dstp)[1] = ((const uint4*)o8)[1];
    }
    return;
  }

  // f16 epilogue (plain / +bias / V tiles): 2 passes through LDS (64 x 128, stride 136)
  unsigned short* Cs = (unsigned short*)C;
#pragma unroll
  for (int p = 0; p < 2; ++p) {
    __syncthreads();
#pragma unroll
    for (int mi = 0; mi < 2; ++mi) {
      int mt = p * 2 + mi;
      int rl = wr * 32 + mi * 16 + quad * 4;
#pragma unroll
      for (int nt = 0; nt < 4; ++nt) {
        int cl = wc * 64 + nt * 16 + l15;
#pragma unroll
        for (int rg = 0; rg < 4; ++rg)
          sh[(rl + rg) * 136 + cl] = f2h(acc[mt][nt][rg] + bv[nt]);
      }
    }
    __syncthreads();
#pragma unroll
    for (int c = 0; c < 4; ++c) {
      int rl = c * 16 + (tid >> 4), cx = tid & 15;
      int grow = tm * 128 + ((rl >> 5) << 6) + p * 32 + (rl & 31);
      uint4 v = *(const uint4*)&sh[rl * 136 + cx * 8];
      *(uint4*)&Cs[(size_t)grow * N + tn * 128 + cx * 8] = v;
    }
  }
}

// ---------------------------------------------------------------- spatial attention (prep'd inputs)
__global__ __launch_bounds__(256) void attn_spatial(
    const unsigned short* __restrict__ qkv, unsigned short* __restrict__ aout) {
  __shared__ __align__(16) unsigned short sh[30720]; // 61440 B
  unsigned short* Kls = sh;          // 128 rows x 64 halves (128B rows, chunk-swizzled)
  unsigned short* Vt = sh + 8192;    // 64 x 224 halves
  unsigned short* P = sh + 22528;    // 4 waves x 2048 halves
  const int tid = threadIdx.x;
  const int w = tid >> 6, lane = tid & 63;
  const int l15 = lane & 15, quad = lane >> 4;
  const int n = blockIdx.x >> 4, h = blockIdx.x & 15;
  const size_t tb = (size_t)n * 220;
  const unsigned short* qbase = qkv + tb * 3072 + h * 64;

  f16x8 aq[4][2];
#pragma unroll
  for (int mt = 0; mt < 4; ++mt) {
    int row = w * 64 + mt * 16 + l15;
    if (row > 219) row = 219;
#pragma unroll
    for (int c = 0; c < 2; ++c)
      aq[mt][c] = *(const f16x8a*)(qbase + (size_t)row * 3072 + c * 32 + quad * 8);
  }
  if (tid < 220) {
    const uint4* src = (const uint4*)(qbase + (size_t)tid * 3072 + 2048);
    uint4 vv[8];
#pragma unroll
    for (int c = 0; c < 8; ++c) vv[c] = src[c];
    const unsigned short* us = (const unsigned short*)vv;
#pragma unroll
    for (int d = 0; d < 64; ++d) Vt[d * 224 + tid] = us[d];
  } else if (tid < 224) {
#pragma unroll
    for (int d = 0; d < 64; ++d) Vt[d * 224 + tid] = 0;
  }

  float lsum[4][4];
  f32x4 o[4][4];
#pragma unroll
  for (int mt = 0; mt < 4; ++mt)
#pragma unroll
    for (int rg = 0; rg < 4; ++rg) lsum[mt][rg] = 0.f;
#pragma unroll
  for (int mt = 0; mt < 4; ++mt)
#pragma unroll
    for (int nt = 0; nt < 4; ++nt) o[mt][nt] = (f32x4){0.f, 0.f, 0.f, 0.f};

  const int xr = (l15 & 3) ^ ((l15 >> 2) & 3);
  unsigned short* Pw = P + w * 2048;

  for (int half = 0; half < 2; ++half) {
    const int k0 = half * 128;
    const int nslot = half ? 736 : 1024;
#pragma unroll
    for (int k = 0; k < 4; ++k) {
      int slot = k * 256 + tid;
      if (slot < nslot) {
        int rl = slot >> 3, c = slot & 7;
        gll16(qbase + (size_t)(k0 + rl) * 3072 + 1024 + ((c ^ (rl & 7)) * 8),
              (char*)Kls + k * 4096 + w * 1024);
      }
    }
    __syncthreads();
    const int nci = half ? 3 : 4;
    for (int ci = 0; ci < nci; ++ci) {
      const int cig = half * 4 + ci;
      f16x8 bk[2][2];
#pragma unroll
      for (int ct = 0; ct < 2; ++ct) {
        int rl = ci * 32 + ct * 16 + l15;
#pragma unroll
        for (int c = 0; c < 2; ++c)
          bk[ct][c] = *(const f16x8a*)((const char*)Kls + rl * 128 + (((quad + 4 * c) ^ (rl & 7)) * 16));
      }
      f32x4 sc[4][2];
#pragma unroll
      for (int mt = 0; mt < 4; ++mt)
#pragma unroll
        for (int ct = 0; ct < 2; ++ct) {
          f32x4 z = (f32x4){0.f, 0.f, 0.f, 0.f};
          z = __builtin_amdgcn_mfma_f32_16x16x32_f16(aq[mt][0], bk[ct][0], z, 0, 0, 0);
          sc[mt][ct] = __builtin_amdgcn_mfma_f32_16x16x32_f16(aq[mt][1], bk[ct][1], z, 0, 0, 0);
        }
      const int okk = (cig * 32 + 16 + l15) < 220;
#pragma unroll
      for (int mt = 0; mt < 4; ++mt)
#pragma unroll
        for (int rg = 0; rg < 4; ++rg) {
          float p0 = exp2f(sc[mt][0][rg]);
          float p1 = okk ? exp2f(sc[mt][1][rg]) : 0.0f;
          lsum[mt][rg] += p0 + p1;
          int xw = quad ^ rg;
          unsigned short* pb = Pw + (mt * 16 + quad * 4 + rg) * 32;
          pb[(((l15 >> 3) ^ xw) * 8) + (l15 & 7)] = f2h(p0);
          pb[(((2 + (l15 >> 3)) ^ xw) * 8) + (l15 & 7)] = f2h(p1);
        }
      __asm__ volatile("s_waitcnt lgkmcnt(0)" ::: "memory");
      f16x8 ap[4], bv[4];
#pragma unroll
      for (int mt = 0; mt < 4; ++mt)
        ap[mt] = *(const f16x8a*)((const char*)Pw + (mt * 16 + l15) * 64 + (quad ^ xr) * 16);
#pragma unroll
      for (int nt = 0; nt < 4; ++nt)
        bv[nt] = *(const f16x8a*)((const char*)Vt + (nt * 16 + l15) * 448 + cig * 64 + quad * 16);
#pragma unroll
      for (int mt = 0; mt < 4; ++mt)
#pragma unroll
        for (int nt = 0; nt < 4; ++nt)
          o[mt][nt] = __builtin_amdgcn_mfma_f32_16x16x32_f16(ap[mt], bv[nt], o[mt][nt], 0, 0, 0);
    }
    __syncthreads();
  }

#pragma unroll
  for (int mt = 0; mt < 4; ++mt)
#pragma unroll
    for (int rg = 0; rg < 4; ++rg) {
      float l = lsum[mt][rg];
      l += __shfl_xor(l, 1);
      l += __shfl_xor(l, 2);
      l += __shfl_xor(l, 4);
      l += __shfl_xor(l, 8);
      int s = w * 64 + mt * 16 + quad * 4 + rg;
      if (s < 220) {
        float inv = 1.0f / l;
        unsigned short* dst = aout + (tb + s) * 1024 + h * 64;
#pragma unroll
        for (int nt = 0; nt < 4; ++nt) dst[nt * 16 + l15] = f2h(o[mt][nt][rg] * inv);
      }
    }
}

// ---------------------------------------------------------------- temporal attention (prep'd inputs)
__global__ __launch_bounds__(256) void attn_temporal(
    const unsigned short* __restrict__ qkv, unsigned short* __restrict__ aout) {
  __shared__ __align__(16) unsigned short sh[14336];
  const int tid = threadIdx.x;
  const int w = tid >> 6, lane = tid & 63;
  const int l15 = lane & 15, quad = lane >> 4;
  const int b = blockIdx.x / 880;
  const int rem = blockIdx.x % 880;
  const int p = rem >> 2, hq = rem & 3;
  const int h = hq * 4 + w;
  unsigned short* Vtw = sh + w * 2560;
  unsigned short* Pw = sh + 10240 + w * 1024;
  const unsigned short* base = qkv + ((size_t)(b * 24) * 220 + p) * 3072 + h * 64;
  const size_t fs = (size_t)220 * 3072;

  {
    int r = lane >> 1, hf = lane & 1;
    if (r < 24) {
      const uint4* src = (const uint4*)(base + r * fs + 2048 + hf * 32);
      uint4 vv[4];
#pragma unroll
      for (int c = 0; c < 4; ++c) vv[c] = src[c];
      const unsigned short* us = (const unsigned short*)vv;
#pragma unroll
      for (int j = 0; j < 32; ++j) Vtw[(hf * 32 + j) * 40 + r] = us[j];
    } else {
#pragma unroll
      for (int j = 0; j < 32; ++j) Vtw[(hf * 32 + j) * 40 + r] = 0;
    }
  }
  f16x8 aq[2][2], bk[2][2];
#pragma unroll
  for (int mt = 0; mt < 2; ++mt) {
    int row = mt * 16 + l15;
    if (row > 23) row = 23;
#pragma unroll
    for (int c = 0; c < 2; ++c)
      aq[mt][c] = *(const f16x8a*)(base + row * fs + c * 32 + quad * 8);
  }
#pragma unroll
  for (int ct = 0; ct < 2; ++ct) {
    int row = ct * 16 + l15;
    if (row > 23) row = 23;
#pragma unroll
    for (int c = 0; c < 2; ++c)
      bk[ct][c] = *(const f16x8a*)(base + row * fs + 1024 + c * 32 + quad * 8);
  }
  f32x4 sc[2][2];
#pragma unroll
  for (int mt = 0; mt < 2; ++mt)
#pragma unroll
    for (int ct = 0; ct < 2; ++ct) {
      f32x4 z = (f32x4){0.f, 0.f, 0.f, 0.f};
      z = __builtin_amdgcn_mfma_f32_16x16x32_f16(aq[mt][0], bk[ct][0], z, 0, 0, 0);
      sc[mt][ct] = __builtin_amdgcn_mfma_f32_16x16x32_f16(aq[mt][1], bk[ct][1], z, 0, 0, 0);
    }
  const int xr = (l15 & 3) ^ ((l15 >> 2) & 3);
  const int okk = l15 < 8;
  float lr[2][4];
#pragma unroll
  for (int mt = 0; mt < 2; ++mt)
#pragma unroll
    for (int rg = 0; rg < 4; ++rg) {
      float p0 = exp2f(sc[mt][0][rg]);
      float p1 = okk ? exp2f(sc[mt][1][rg]) : 0.0f;
      float rs = p0 + p1;
      rs += __shfl_xor(rs, 1);
      rs += __shfl_xor(rs, 2);
      rs += __shfl_xor(rs, 4);
      rs += __shfl_xor(rs, 8);
      lr[mt][rg] = rs;
      int xw = quad ^ rg;
      unsigned short* pb = Pw + (mt * 16 + quad * 4 + rg) * 32;
      pb[(((l15 >> 3) ^ xw) * 8) + (l15 & 7)] = f2h(p0);
      pb[(((2 + (l15 >> 3)) ^ xw) * 8) + (l15 & 7)] = f2h(p1);
    }
  __asm__ volatile("s_waitcnt lgkmcnt(0)" ::: "memory");
  f16x8 ap[2], bv[4];
#pragma unroll
  for (int mt = 0; mt < 2; ++mt)
    ap[mt] = *(const f16x8a*)((const char*)Pw + (mt * 16 + l15) * 64 + (quad ^ xr) * 16);
#pragma unroll
  for (int nt = 0; nt < 4; ++nt)
    bv[nt] = *(const f16x8a*)((const char*)Vtw + (nt * 16 + l15) * 80 + quad * 16);
  f32x4 o[2][4];
#pragma unroll
  for (int mt = 0; mt < 2; ++mt)
#pragma unroll
    for (int nt = 0; nt < 4; ++nt) {
      f32x4 z = (f32x4){0.f, 0.f, 0.f, 0.f};
      o[mt][nt] = __builtin_amdgcn_mfma_f32_16x16x32_f16(ap[mt], bv[nt], z, 0, 0, 0);
    }
#pragma unroll
  for (int mt = 0; mt < 2; ++mt)
#pragma unroll
    for (int rg = 0; rg < 4; ++rg) {
      int s = mt * 16 + quad * 4 + rg;
      if (s < 24) {
        float inv = 1.0f / lr[mt][rg];
        unsigned short* dst = aout + ((size_t)(b * 24 + s) * 220 + p) * 1024 + h * 64;
#pragma unroll
        for (int nt = 0; nt < 4; ++nt) dst[nt * 16 + l15] = f2h(o[mt][nt][rg] * inv);
      }
    }
}

// ---------------------------------------------------------------- launch
extern "C" void kernel_launch(void* const* d_in, const int* in_sizes, int n_in,
                              void* d_out, int out_size, void* d_ws, size_t ws_size,
                              hipStream_t stream) {
  (void)in_sizes; (void)n_in; (void)out_size; (void)ws_size;
  const float* x = (const float*)d_in[0];
  const float* wsqkv = (const float*)d_in[1];
  const float* wsproj = (const float*)d_in[2];
  const float* bsproj = (const float*)d_in[3];
  const float* wtqkv = (const float*)d_in[4];
  const float* wtproj = (const float*)d_in[5];
  const float* btproj = (const float*)d_in[6];
  const float* sqg = (const float*)d_in[7];
  const float* skg = (const float*)d_in[8];
  const float* tqg = (const float*)d_in[9];
  const float* tkg = (const float*)d_in[10];

  char* ws = (char*)d_ws;
  size_t off = 0;
  auto alloc = [&](size_t bytes) {
    char* ptr = ws + off;
    off += (bytes + 255) & ~(size_t)255;
    return ptr;
  };
  unsigned short* xb = (unsigned short*)alloc((size_t)NTOK * 1024 * 2);
  unsigned short* qkvb = (unsigned short*)alloc((size_t)NTOK * 3072 * 2);
  unsigned short* aoutb = (unsigned short*)alloc((size_t)NTOK * 1024 * 2);
  unsigned short* wsqkvb = (unsigned short*)alloc((size_t)3072 * 1024 * 2);
  unsigned short* wsprojb = (unsigned short*)alloc((size_t)1024 * 1024 * 2);
  unsigned short* wtqkvb = (unsigned short*)alloc((size_t)3072 * 1024 * 2);
  unsigned short* wtprojb = (unsigned short*)alloc((size_t)1024 * 1024 * 2);
  float2* tabS = (float2*)alloc(220 * 32 * 8);
  float2* tabT = (float2*)alloc(24 * 32 * 8);

  dim3 blk(256);
  cast_kernel<<<21120, blk, 0, stream>>>(x, xb, 5406720);
  cast_kernel<<<3072, blk, 0, stream>>>(wsqkv, wsqkvb, 786432);
  cast_kernel<<<1024, blk, 0, stream>>>(wsproj, wsprojb, 262144);
  cast_kernel<<<3072, blk, 0, stream>>>(wtqkv, wtqkvb, 786432);
  cast_kernel<<<1024, blk, 0, stream>>>(wtproj, wtprojb, 262144);
  rope_table_kernel<<<31, blk, 0, stream>>>(tabS, tabT);

  // stage S
  gemm_bt<<<dim3(165 * 24), blk, 0, stream>>>(xb, wsqkvb, nullptr, qkvb, NTOK, 3072, 1024, 3,
                                              tabS, sqg, skg, 0);
  attn_spatial<<<dim3(1536), blk, 0, stream>>>(qkvb, aoutb);
  gemm_bt<<<dim3(165 * 8), blk, 0, stream>>>(aoutb, wsprojb, bsproj, xb, NTOK, 1024, 1024, 1,
                                             nullptr, nullptr, nullptr, 0);
  // stage T
  gemm_bt<<<dim3(165 * 24), blk, 0, stream>>>(xb, wtqkvb, nullptr, qkvb, NTOK, 3072, 1024, 3,
                                              tabT, tqg, tkg, 1);
  attn_temporal<<<dim3(3520), blk, 0, stream>>>(qkvb, aoutb);
  gemm_bt<<<dim3(165 * 8), blk, 0, stream>>>(aoutb, wtprojb, btproj, (float*)d_out, NTOK, 1024, 1024, 2,
                                             nullptr, nullptr, nullptr, 0);
}

// Round 6
// 791.705 us; speedup vs baseline: 1.4276x; 1.0646x over previous
//
#include <hip/hip_runtime.h>

typedef _Float16 f16;
typedef _Float16 f16x8 __attribute__((ext_vector_type(8)));
typedef f16x8 f16x8a __attribute__((may_alias));
typedef float f32x4 __attribute__((ext_vector_type(4)));

#define NTOK 21120          // 4 * 5280 tokens
#define SCALE_Q 0.18033688f // (1/8) * log2(e)

__device__ __forceinline__ void gll16(const void* g, void* l) {
  __builtin_amdgcn_global_load_lds(
      (const __attribute__((address_space(1))) unsigned int*)g,
      (__attribute__((address_space(3))) unsigned int*)l, 16, 0, 0);
}

__device__ __forceinline__ unsigned int pack2(float a, float b) {
  union { f16 h[2]; unsigned int u; } c;
  c.h[0] = (f16)a; c.h[1] = (f16)b;
  return c.u;
}
__device__ __forceinline__ unsigned short f2h(float a) {
  union { f16 h; unsigned short u; } c; c.h = (f16)a; return c.u;
}

// ---------------------------------------------------------------- casts
__global__ __launch_bounds__(256) void cast_kernel(
    const float* __restrict__ in, unsigned short* __restrict__ out, int n4) {
  int i = blockIdx.x * 256 + threadIdx.x;
  if (i >= n4) return;
  float4 v = ((const float4*)in)[i];
  uint2 o;
  o.x = pack2(v.x, v.y);
  o.y = pack2(v.z, v.w);
  ((uint2*)out)[i] = o;
}

// transpose + cast 1024x1024 f32 -> f16 (out[d][c] = in[c][d])
__global__ __launch_bounds__(256) void transpose_cast_kernel(
    const float* __restrict__ in, unsigned short* __restrict__ out) {
  __shared__ float tile[32][33];
  int bx = blockIdx.x & 31, by = blockIdx.x >> 5;
  int tx = threadIdx.x & 31, ty = threadIdx.x >> 5;
#pragma unroll
  for (int i = 0; i < 32; i += 8)
    tile[ty + i][tx] = in[(size_t)(by * 32 + ty + i) * 1024 + bx * 32 + tx];
  __syncthreads();
#pragma unroll
  for (int i = 0; i < 32; i += 8)
    out[(size_t)(bx * 32 + ty + i) * 1024 + by * 32 + tx] = f2h(tile[tx][ty + i]);
}

// bc[e] = sum_c wtqkv[e][c] * bsproj[c]   (e in [0,3072))
__global__ __launch_bounds__(256) void bias_combine_kernel(
    const float* __restrict__ w, const float* __restrict__ b, float* __restrict__ bc) {
  int e = blockIdx.x * 256 + threadIdx.x;
  if (e >= 3072) return;
  const float4* wr = (const float4*)(w + (size_t)e * 1024);
  const float4* b4 = (const float4*)b;
  float s = 0.f;
  for (int c = 0; c < 256; ++c) {
    float4 wv = wr[c], bv = b4[c];
    s += wv.x * bv.x + wv.y * bv.y + wv.z * bv.z + wv.w * bv.w;
  }
  bc[e] = s;
}

// ---------------------------------------------------------------- rope tables
__global__ __launch_bounds__(256) void rope_table_kernel(float2* tabS, float2* tabT) {
  int t = blockIdx.x * 256 + threadIdx.x;
  const float lb = logf(10000.0f) * (1.0f / 32.0f);
  if (t < 220 * 32) {
    int s = t >> 5, i = t & 31;
    float theta = expf(-(float)i * lb);
    float ang = (float)s * theta;
    tabS[t] = make_float2(cosf(ang), sinf(ang));
  } else if (t < 220 * 32 + 24 * 32) {
    int u = t - 220 * 32;
    int s = u >> 5, i = u & 31;
    float theta = expf(-(float)i * lb);
    float ang = (float)s * theta;
    tabT[u] = make_float2(cosf(ang), sinf(ang));
  }
}

// ---------------------------------------------------------------- GEMM  C = A * B^T
// A[M,K], B[N,K] f16 K-contiguous. BK=64 (32 KB LDS), 1D grid supertile swizzle.
// outmode: 0 = f16, 1 = f16 + bias, 2 = f32 + bias (coalesced via LDS),
//          3 = fused QKV prep (N=3072): tn<8 -> Q (+bias, rmsnorm+gain+rope+SCALE_Q),
//              tn in [8,16) -> K (+bias, rmsnorm+gain+rope), tn>=16 -> V f16 (+bias).
//              bias may be null (stage S).
__global__ __launch_bounds__(256) void gemm_bt(
    const unsigned short* __restrict__ A, const unsigned short* __restrict__ B,
    const float* __restrict__ bias, void* __restrict__ C,
    int M, int N, int K, int outmode,
    const float2* __restrict__ tab, const float* __restrict__ gq,
    const float* __restrict__ gk, int mode) {
  __shared__ __align__(16) unsigned short sh[16384]; // 32 KB: staging / epilogue
  unsigned short* As = sh;        // 128 rows x 64 f16 (128B rows, chunk-swizzled)
  unsigned short* Bs = sh + 8192;
  const int tid = threadIdx.x;
  const int w = tid >> 6, lane = tid & 63;
  const int l15 = lane & 15, quad = lane >> 4;
  const int wr = w >> 1, wc = w & 1;

  // supertile swizzle: groups of 8 tm x ntn blocks
  const int ntn = N >> 7;
  const int stride = ntn << 3;
  const int g = blockIdx.x / stride, r = blockIdx.x % stride;
  const int tn = r % ntn, tm = g * 8 + r / ntn;

  f32x4 acc[4][4];
#pragma unroll
  for (int a = 0; a < 4; ++a)
#pragma unroll
    for (int b = 0; b < 4; ++b) acc[a][b] = (f32x4){0.f, 0.f, 0.f, 0.f};

  const int srow = tid >> 3;      // row-in-32 per staging round
  const int schk = tid & 7;       // chunk slot 0..7
  const size_t arow0 = (size_t)tm * 128;
  const size_t brow0 = (size_t)tn * 128;
  const int nk = K >> 6;

  for (int kt = 0; kt < nk; ++kt) {
    __syncthreads();
    const int kb = kt << 6;
#pragma unroll
    for (int rd = 0; rd < 4; ++rd) {
      int row = rd * 32 + srow;
      int sc = (schk ^ (row & 7)) * 8;
      gll16(A + (arow0 + row) * K + kb + sc, (char*)As + rd * 4096 + tid * 16);
      gll16(B + (brow0 + row) * K + kb + sc, (char*)Bs + rd * 4096 + tid * 16);
    }
    __syncthreads();
#pragma unroll
    for (int kk = 0; kk < 2; ++kk) {
      f16x8 af[4], bf[4];
#pragma unroll
      for (int mt = 0; mt < 4; ++mt) {
        int ra = wr * 64 + mt * 16 + l15;
        af[mt] = *(const f16x8a*)((const char*)As + ra * 128 + (((kk * 4 + quad) ^ (ra & 7)) * 16));
        int rb = wc * 64 + mt * 16 + l15;
        bf[mt] = *(const f16x8a*)((const char*)Bs + rb * 128 + (((kk * 4 + quad) ^ (rb & 7)) * 16));
      }
#pragma unroll
      for (int mt = 0; mt < 4; ++mt)
#pragma unroll
        for (int nt = 0; nt < 4; ++nt)
          acc[mt][nt] = __builtin_amdgcn_mfma_f32_16x16x32_f16(af[mt], bf[nt], acc[mt][nt], 0, 0, 0);
    }
  }

  float bv[4];
#pragma unroll
  for (int nt = 0; nt < 4; ++nt) bv[nt] = 0.f;
  if (bias != nullptr && outmode != 3) {
#pragma unroll
    for (int nt = 0; nt < 4; ++nt) bv[nt] = bias[tn * 128 + wc * 64 + nt * 16 + l15];
  }

  if (outmode == 2) {
    // f32 + bias, coalesced: per-mt pass through LDS (32 rows x 128 f32, stride 132)
    float* shf = (float*)sh;
#pragma unroll
    for (int mt = 0; mt < 4; ++mt) {
      __syncthreads();
#pragma unroll
      for (int nt = 0; nt < 4; ++nt)
#pragma unroll
        for (int rg = 0; rg < 4; ++rg)
          shf[(wr * 16 + quad * 4 + rg) * 132 + wc * 64 + nt * 16 + l15] = acc[mt][nt][rg] + bv[nt];
      __syncthreads();
      int l = tid >> 3, c8 = tid & 7;
      int grow = tm * 128 + ((l >> 4) << 6) + mt * 16 + (l & 15);
      float4* dst = (float4*)((float*)C + (size_t)grow * N + tn * 128 + c8 * 16);
      const float4* srcp = (const float4*)(shf + l * 132 + c8 * 16);
#pragma unroll
      for (int c = 0; c < 4; ++c) dst[c] = srcp[c];
    }
    return;
  }

  if (outmode == 3 && tn < 16) {
    // fused (+bias) RMSNorm + gain + RoPE epilogue for Q/K tiles (2 heads per tile)
    const int qtile = tn < 8;
    const float* gg = qtile ? gq : gk;
    float* shf = (float*)sh;
    const int sub = tid & 3, pr = tid >> 2;
    const int l = pr >> 1, head = pr & 1;
    float bl[16];
    if (bias != nullptr) {
      const float4* bsrc = (const float4*)(bias + tn * 128 + head * 64 + sub * 16);
#pragma unroll
      for (int c = 0; c < 4; ++c) {
        float4 bb = bsrc[c];
        bl[c * 4 + 0] = bb.x; bl[c * 4 + 1] = bb.y; bl[c * 4 + 2] = bb.z; bl[c * 4 + 3] = bb.w;
      }
    } else {
#pragma unroll
      for (int j = 0; j < 16; ++j) bl[j] = 0.f;
    }
#pragma unroll
    for (int mt = 0; mt < 4; ++mt) {
      __syncthreads();
#pragma unroll
      for (int nt = 0; nt < 4; ++nt)
#pragma unroll
        for (int rg = 0; rg < 4; ++rg)
          shf[(wr * 16 + quad * 4 + rg) * 132 + wc * 64 + nt * 16 + l15] = acc[mt][nt][rg];
      __syncthreads();
      int grow = tm * 128 + ((l >> 4) << 6) + mt * 16 + (l & 15);
      int pos = (mode == 0) ? (grow % 220) : ((grow / 220) % 24);
      float v[16];
      const float4* vsrc = (const float4*)(shf + l * 132 + head * 64 + sub * 16);
#pragma unroll
      for (int c = 0; c < 4; ++c) {
        float4 t4 = vsrc[c];
        v[c * 4 + 0] = t4.x + bl[c * 4 + 0];
        v[c * 4 + 1] = t4.y + bl[c * 4 + 1];
        v[c * 4 + 2] = t4.z + bl[c * 4 + 2];
        v[c * 4 + 3] = t4.w + bl[c * 4 + 3];
      }
      float ssq = 0.f;
#pragma unroll
      for (int j = 0; j < 16; ++j) ssq += v[j] * v[j];
      ssq += __shfl_xor(ssq, 1);
      ssq += __shfl_xor(ssq, 2);
      float rr = rsqrtf(ssq * (1.0f / 64.0f) + 1e-6f);
      if (qtile) rr *= SCALE_Q;
      const float2* cs = tab + pos * 32 + sub * 8;
      const float2* g2 = (const float2*)gg + sub * 8;
      unsigned int o8[8];
#pragma unroll
      for (int jj = 0; jj < 8; ++jj) {
        float2 c = cs[jj], gp = g2[jj];
        float a = v[2 * jj] * rr * gp.x, b = v[2 * jj + 1] * rr * gp.y;
        o8[jj] = pack2(a * c.x - b * c.y, b * c.x + a * c.y);
      }
      unsigned short* dstp = (unsigned short*)C + (size_t)grow * N + tn * 128 + head * 64 + sub * 16;
      ((uint4*)dstp)[0] = ((const uint4*)o8)[0];
      ((uint4*)dstp)[1] = ((const uint4*)o8)[1];
    }
    return;
  }

  if (outmode == 3 && bias != nullptr) {
#pragma unroll
    for (int nt = 0; nt < 4; ++nt) bv[nt] = bias[tn * 128 + wc * 64 + nt * 16 + l15];
  }

  // f16 epilogue (plain / +bias / V tiles): 2 passes through LDS (64 x 128, stride 136)
  unsigned short* Cs = (unsigned short*)C;
#pragma unroll
  for (int p = 0; p < 2; ++p) {
    __syncthreads();
#pragma unroll
    for (int mi = 0; mi < 2; ++mi) {
      int mt = p * 2 + mi;
      int rl = wr * 32 + mi * 16 + quad * 4;
#pragma unroll
      for (int nt = 0; nt < 4; ++nt) {
        int cl = wc * 64 + nt * 16 + l15;
#pragma unroll
        for (int rg = 0; rg < 4; ++rg)
          sh[(rl + rg) * 136 + cl] = f2h(acc[mt][nt][rg] + bv[nt]);
      }
    }
    __syncthreads();
#pragma unroll
    for (int c = 0; c < 4; ++c) {
      int rl = c * 16 + (tid >> 4), cx = tid & 15;
      int grow = tm * 128 + ((rl >> 5) << 6) + p * 32 + (rl & 31);
      uint4 v = *(const uint4*)&sh[rl * 136 + cx * 8];
      *(uint4*)&Cs[(size_t)grow * N + tn * 128 + cx * 8] = v;
    }
  }
}

// ---------------------------------------------------------------- spatial attention (prep'd inputs)
__global__ __launch_bounds__(256) void attn_spatial(
    const unsigned short* __restrict__ qkv, unsigned short* __restrict__ aout) {
  __shared__ __align__(16) unsigned short sh[30720]; // 61440 B
  unsigned short* Kls = sh;          // 128 rows x 64 halves (128B rows, chunk-swizzled)
  unsigned short* Vt = sh + 8192;    // 64 x 224 halves
  unsigned short* P = sh + 22528;    // 4 waves x 2048 halves
  const int tid = threadIdx.x;
  const int w = tid >> 6, lane = tid & 63;
  const int l15 = lane & 15, quad = lane >> 4;
  const int n = blockIdx.x >> 4, h = blockIdx.x & 15;
  const size_t tb = (size_t)n * 220;
  const unsigned short* qbase = qkv + tb * 3072 + h * 64;

  f16x8 aq[4][2];
#pragma unroll
  for (int mt = 0; mt < 4; ++mt) {
    int row = w * 64 + mt * 16 + l15;
    if (row > 219) row = 219;
#pragma unroll
    for (int c = 0; c < 2; ++c)
      aq[mt][c] = *(const f16x8a*)(qbase + (size_t)row * 3072 + c * 32 + quad * 8);
  }
  if (tid < 220) {
    const uint4* src = (const uint4*)(qbase + (size_t)tid * 3072 + 2048);
    uint4 vv[8];
#pragma unroll
    for (int c = 0; c < 8; ++c) vv[c] = src[c];
    const unsigned short* us = (const unsigned short*)vv;
#pragma unroll
    for (int d = 0; d < 64; ++d) Vt[d * 224 + tid] = us[d];
  } else if (tid < 224) {
#pragma unroll
    for (int d = 0; d < 64; ++d) Vt[d * 224 + tid] = 0;
  }

  float lsum[4][4];
  f32x4 o[4][4];
#pragma unroll
  for (int mt = 0; mt < 4; ++mt)
#pragma unroll
    for (int rg = 0; rg < 4; ++rg) lsum[mt][rg] = 0.f;
#pragma unroll
  for (int mt = 0; mt < 4; ++mt)
#pragma unroll
    for (int nt = 0; nt < 4; ++nt) o[mt][nt] = (f32x4){0.f, 0.f, 0.f, 0.f};

  const int xr = (l15 & 3) ^ ((l15 >> 2) & 3);
  unsigned short* Pw = P + w * 2048;

  for (int half = 0; half < 2; ++half) {
    const int k0 = half * 128;
    const int nslot = half ? 736 : 1024;
#pragma unroll
    for (int k = 0; k < 4; ++k) {
      int slot = k * 256 + tid;
      if (slot < nslot) {
        int rl = slot >> 3, c = slot & 7;
        gll16(qbase + (size_t)(k0 + rl) * 3072 + 1024 + ((c ^ (rl & 7)) * 8),
              (char*)Kls + k * 4096 + w * 1024);
      }
    }
    __syncthreads();
    const int nci = half ? 3 : 4;
    for (int ci = 0; ci < nci; ++ci) {
      const int cig = half * 4 + ci;
      f16x8 bk[2][2];
#pragma unroll
      for (int ct = 0; ct < 2; ++ct) {
        int rl = ci * 32 + ct * 16 + l15;
#pragma unroll
        for (int c = 0; c < 2; ++c)
          bk[ct][c] = *(const f16x8a*)((const char*)Kls + rl * 128 + (((quad + 4 * c) ^ (rl & 7)) * 16));
      }
      f32x4 sc[4][2];
#pragma unroll
      for (int mt = 0; mt < 4; ++mt)
#pragma unroll
        for (int ct = 0; ct < 2; ++ct) {
          f32x4 z = (f32x4){0.f, 0.f, 0.f, 0.f};
          z = __builtin_amdgcn_mfma_f32_16x16x32_f16(aq[mt][0], bk[ct][0], z, 0, 0, 0);
          sc[mt][ct] = __builtin_amdgcn_mfma_f32_16x16x32_f16(aq[mt][1], bk[ct][1], z, 0, 0, 0);
        }
      const int okk = (cig * 32 + 16 + l15) < 220;
#pragma unroll
      for (int mt = 0; mt < 4; ++mt)
#pragma unroll
        for (int rg = 0; rg < 4; ++rg) {
          float p0 = exp2f(sc[mt][0][rg]);
          float p1 = okk ? exp2f(sc[mt][1][rg]) : 0.0f;
          lsum[mt][rg] += p0 + p1;
          int xw = quad ^ rg;
          unsigned short* pb = Pw + (mt * 16 + quad * 4 + rg) * 32;
          pb[(((l15 >> 3) ^ xw) * 8) + (l15 & 7)] = f2h(p0);
          pb[(((2 + (l15 >> 3)) ^ xw) * 8) + (l15 & 7)] = f2h(p1);
        }
      __asm__ volatile("s_waitcnt lgkmcnt(0)" ::: "memory");
      f16x8 ap[4], bv[4];
#pragma unroll
      for (int mt = 0; mt < 4; ++mt)
        ap[mt] = *(const f16x8a*)((const char*)Pw + (mt * 16 + l15) * 64 + (quad ^ xr) * 16);
#pragma unroll
      for (int nt = 0; nt < 4; ++nt)
        bv[nt] = *(const f16x8a*)((const char*)Vt + (nt * 16 + l15) * 448 + cig * 64 + quad * 16);
#pragma unroll
      for (int mt = 0; mt < 4; ++mt)
#pragma unroll
        for (int nt = 0; nt < 4; ++nt)
          o[mt][nt] = __builtin_amdgcn_mfma_f32_16x16x32_f16(ap[mt], bv[nt], o[mt][nt], 0, 0, 0);
    }
    __syncthreads();
  }

#pragma unroll
  for (int mt = 0; mt < 4; ++mt)
#pragma unroll
    for (int rg = 0; rg < 4; ++rg) {
      float l = lsum[mt][rg];
      l += __shfl_xor(l, 1);
      l += __shfl_xor(l, 2);
      l += __shfl_xor(l, 4);
      l += __shfl_xor(l, 8);
      int s = w * 64 + mt * 16 + quad * 4 + rg;
      if (s < 220) {
        float inv = 1.0f / l;
        unsigned short* dst = aout + (tb + s) * 1024 + h * 64;
#pragma unroll
        for (int nt = 0; nt < 4; ++nt) dst[nt * 16 + l15] = f2h(o[mt][nt][rg] * inv);
      }
    }
}

// ---------------------------------------------------------------- temporal attention (prep'd inputs)
__global__ __launch_bounds__(256) void attn_temporal(
    const unsigned short* __restrict__ qkv, unsigned short* __restrict__ aout) {
  __shared__ __align__(16) unsigned short sh[14336];
  const int tid = threadIdx.x;
  const int w = tid >> 6, lane = tid & 63;
  const int l15 = lane & 15, quad = lane >> 4;
  const int b = blockIdx.x / 880;
  const int rem = blockIdx.x % 880;
  const int p = rem >> 2, hq = rem & 3;
  const int h = hq * 4 + w;
  unsigned short* Vtw = sh + w * 2560;
  unsigned short* Pw = sh + 10240 + w * 1024;
  const unsigned short* base = qkv + ((size_t)(b * 24) * 220 + p) * 3072 + h * 64;
  const size_t fs = (size_t)220 * 3072;

  {
    int r = lane >> 1, hf = lane & 1;
    if (r < 24) {
      const uint4* src = (const uint4*)(base + r * fs + 2048 + hf * 32);
      uint4 vv[4];
#pragma unroll
      for (int c = 0; c < 4; ++c) vv[c] = src[c];
      const unsigned short* us = (const unsigned short*)vv;
#pragma unroll
      for (int j = 0; j < 32; ++j) Vtw[(hf * 32 + j) * 40 + r] = us[j];
    } else {
#pragma unroll
      for (int j = 0; j < 32; ++j) Vtw[(hf * 32 + j) * 40 + r] = 0;
    }
  }
  f16x8 aq[2][2], bk[2][2];
#pragma unroll
  for (int mt = 0; mt < 2; ++mt) {
    int row = mt * 16 + l15;
    if (row > 23) row = 23;
#pragma unroll
    for (int c = 0; c < 2; ++c)
      aq[mt][c] = *(const f16x8a*)(base + row * fs + c * 32 + quad * 8);
  }
#pragma unroll
  for (int ct = 0; ct < 2; ++ct) {
    int row = ct * 16 + l15;
    if (row > 23) row = 23;
#pragma unroll
    for (int c = 0; c < 2; ++c)
      bk[ct][c] = *(const f16x8a*)(base + row * fs + 1024 + c * 32 + quad * 8);
  }
  f32x4 sc[2][2];
#pragma unroll
  for (int mt = 0; mt < 2; ++mt)
#pragma unroll
    for (int ct = 0; ct < 2; ++ct) {
      f32x4 z = (f32x4){0.f, 0.f, 0.f, 0.f};
      z = __builtin_amdgcn_mfma_f32_16x16x32_f16(aq[mt][0], bk[ct][0], z, 0, 0, 0);
      sc[mt][ct] = __builtin_amdgcn_mfma_f32_16x16x32_f16(aq[mt][1], bk[ct][1], z, 0, 0, 0);
    }
  const int xr = (l15 & 3) ^ ((l15 >> 2) & 3);
  const int okk = l15 < 8;
  float lr[2][4];
#pragma unroll
  for (int mt = 0; mt < 2; ++mt)
#pragma unroll
    for (int rg = 0; rg < 4; ++rg) {
      float p0 = exp2f(sc[mt][0][rg]);
      float p1 = okk ? exp2f(sc[mt][1][rg]) : 0.0f;
      float rs = p0 + p1;
      rs += __shfl_xor(rs, 1);
      rs += __shfl_xor(rs, 2);
      rs += __shfl_xor(rs, 4);
      rs += __shfl_xor(rs, 8);
      lr[mt][rg] = rs;
      int xw = quad ^ rg;
      unsigned short* pb = Pw + (mt * 16 + quad * 4 + rg) * 32;
      pb[(((l15 >> 3) ^ xw) * 8) + (l15 & 7)] = f2h(p0);
      pb[(((2 + (l15 >> 3)) ^ xw) * 8) + (l15 & 7)] = f2h(p1);
    }
  __asm__ volatile("s_waitcnt lgkmcnt(0)" ::: "memory");
  f16x8 ap[2], bv[4];
#pragma unroll
  for (int mt = 0; mt < 2; ++mt)
    ap[mt] = *(const f16x8a*)((const char*)Pw + (mt * 16 + l15) * 64 + (quad ^ xr) * 16);
#pragma unroll
  for (int nt = 0; nt < 4; ++nt)
    bv[nt] = *(const f16x8a*)((const char*)Vtw + (nt * 16 + l15) * 80 + quad * 16);
  f32x4 o[2][4];
#pragma unroll
  for (int mt = 0; mt < 2; ++mt)
#pragma unroll
    for (int nt = 0; nt < 4; ++nt) {
      f32x4 z = (f32x4){0.f, 0.f, 0.f, 0.f};
      o[mt][nt] = __builtin_amdgcn_mfma_f32_16x16x32_f16(ap[mt], bv[nt], z, 0, 0, 0);
    }
#pragma unroll
  for (int mt = 0; mt < 2; ++mt)
#pragma unroll
    for (int rg = 0; rg < 4; ++rg) {
      int s = mt * 16 + quad * 4 + rg;
      if (s < 24) {
        float inv = 1.0f / lr[mt][rg];
        unsigned short* dst = aout + ((size_t)(b * 24 + s) * 220 + p) * 1024 + h * 64;
#pragma unroll
        for (int nt = 0; nt < 4; ++nt) dst[nt * 16 + l15] = f2h(o[mt][nt][rg] * inv);
      }
    }
}

// ---------------------------------------------------------------- launch
extern "C" void kernel_launch(void* const* d_in, const int* in_sizes, int n_in,
                              void* d_out, int out_size, void* d_ws, size_t ws_size,
                              hipStream_t stream) {
  (void)in_sizes; (void)n_in; (void)out_size; (void)ws_size;
  const float* x = (const float*)d_in[0];
  const float* wsqkv = (const float*)d_in[1];
  const float* wsproj = (const float*)d_in[2];
  const float* bsproj = (const float*)d_in[3];
  const float* wtqkv = (const float*)d_in[4];
  const float* wtproj = (const float*)d_in[5];
  const float* btproj = (const float*)d_in[6];
  const float* sqg = (const float*)d_in[7];
  const float* skg = (const float*)d_in[8];
  const float* tqg = (const float*)d_in[9];
  const float* tkg = (const float*)d_in[10];

  char* ws = (char*)d_ws;
  size_t off = 0;
  auto alloc = [&](size_t bytes) {
    char* ptr = ws + off;
    off += (bytes + 255) & ~(size_t)255;
    return ptr;
  };
  unsigned short* xb = (unsigned short*)alloc((size_t)NTOK * 1024 * 2);
  unsigned short* qkvb = (unsigned short*)alloc((size_t)NTOK * 3072 * 2);
  unsigned short* aoutb = (unsigned short*)alloc((size_t)NTOK * 1024 * 2);
  unsigned short* wsqkvb = (unsigned short*)alloc((size_t)3072 * 1024 * 2);
  unsigned short* wsprojTb = (unsigned short*)alloc((size_t)1024 * 1024 * 2);
  unsigned short* wtqkvb = (unsigned short*)alloc((size_t)3072 * 1024 * 2);
  unsigned short* wtprojb = (unsigned short*)alloc((size_t)1024 * 1024 * 2);
  unsigned short* wcb = (unsigned short*)alloc((size_t)3072 * 1024 * 2);
  float* bcb = (float*)alloc(3072 * 4);
  float2* tabS = (float2*)alloc(220 * 32 * 8);
  float2* tabT = (float2*)alloc(24 * 32 * 8);

  dim3 blk(256);
  cast_kernel<<<21120, blk, 0, stream>>>(x, xb, 5406720);
  cast_kernel<<<3072, blk, 0, stream>>>(wsqkv, wsqkvb, 786432);
  cast_kernel<<<3072, blk, 0, stream>>>(wtqkv, wtqkvb, 786432);
  cast_kernel<<<1024, blk, 0, stream>>>(wtproj, wtprojb, 262144);
  transpose_cast_kernel<<<1024, blk, 0, stream>>>(wsproj, wsprojTb);
  bias_combine_kernel<<<12, blk, 0, stream>>>(wtqkv, bsproj, bcb);
  rope_table_kernel<<<31, blk, 0, stream>>>(tabS, tabT);

  // Wc = Wtqkv * Wsproj  (so qkv_t = out_s * Wc^T + bc)
  gemm_bt<<<dim3(24 * 8), blk, 0, stream>>>(wtqkvb, wsprojTb, nullptr, wcb, 3072, 1024, 1024, 0,
                                            nullptr, nullptr, nullptr, 0);

  // stage S: fused QKV + prep
  gemm_bt<<<dim3(165 * 24), blk, 0, stream>>>(xb, wsqkvb, nullptr, qkvb, NTOK, 3072, 1024, 3,
                                              tabS, sqg, skg, 0);
  attn_spatial<<<dim3(1536), blk, 0, stream>>>(qkvb, aoutb);
  // stage T: (proj_S ∘ QKV_T) folded into one GEMM with combined weight + bias, fused prep
  gemm_bt<<<dim3(165 * 24), blk, 0, stream>>>(aoutb, wcb, bcb, qkvb, NTOK, 3072, 1024, 3,
                                              tabT, tqg, tkg, 1);
  attn_temporal<<<dim3(3520), blk, 0, stream>>>(qkvb, aoutb);
  gemm_bt<<<dim3(165 * 8), blk, 0, stream>>>(aoutb, wtprojb, btproj, (float*)d_out, NTOK, 1024, 1024, 2,
                                             nullptr, nullptr, nullptr, 0);
}